// Round 1
// baseline (3020.249 us; speedup 1.0000x reference)
//
#include <hip/hip_runtime.h>
#include <cstdint>
#include <cstddef>

#define MEAN_C 0.1307f
#define SIGMA_C 0.3081f
#define SIG_SCALE_C 5.0f

// ---------------- device helpers ----------------

__device__ __forceinline__ float sigmoidf_(float x) {
    if (x >= 0.f) { float e = __expf(-x); return 1.f / (1.f + e); }
    float e = __expf(x); return e / (1.f + e);
}

__device__ __forceinline__ float spu_f(float x) {
    return (x >= 0.f) ? (x * x - 0.5f) : (sigmoidf_(-x) - 1.f);
}

// block = 256 threads (4 waves) exactly
template <int NV>
__device__ __forceinline__ void block_reduce_sum(float* v) {
    #pragma unroll
    for (int o = 32; o > 0; o >>= 1) {
        #pragma unroll
        for (int i = 0; i < NV; ++i) v[i] += __shfl_down(v[i], o, 64);
    }
    __shared__ float sh[NV][4];
    int lane = threadIdx.x & 63, wid = threadIdx.x >> 6;
    if (lane == 0) {
        #pragma unroll
        for (int i = 0; i < NV; ++i) sh[i][wid] = v[i];
    }
    __syncthreads();
    if (threadIdx.x == 0) {
        #pragma unroll
        for (int i = 0; i < NV; ++i) v[i] = sh[i][0] + sh[i][1] + sh[i][2] + sh[i][3];
    }
}

// ---------------- kernels ----------------

__global__ void k_input_bounds(const float* __restrict__ x, const float* __restrict__ eps,
                               int n, float* __restrict__ ubn, float* __restrict__ lbn) {
    int i = blockIdx.x * blockDim.x + threadIdx.x;
    if (i >= n) return;
    float e = eps[0];
    float ub = fminf(x[i] + e, 1.f);
    float lb = fmaxf(x[i] - e, 0.f);
    ubn[i] = (ub - MEAN_C) / SIGMA_C;
    lbn[i] = (lb - MEAN_C) / SIGMA_C;
}

// one block per output row: u_i = sum_j (W>0?U:L)*W + b ; l_i = sum_j (W>0?L:U)*W + b
__global__ __launch_bounds__(256) void k_interval_affine(
        const float* __restrict__ W, const float* __restrict__ b,
        const float* __restrict__ U, const float* __restrict__ L,
        int m, float* __restrict__ uo, float* __restrict__ lo) {
    int i = blockIdx.x;
    const float* Wr = W + (size_t)i * m;
    float acc[2] = {0.f, 0.f};
    for (int j = threadIdx.x; j < m; j += 256) {
        float w = Wr[j];
        float uu = U[j], ll = L[j];
        float bu = (w > 0.f) ? uu : ll;
        float bl = (w > 0.f) ? ll : uu;
        acc[0] += bu * w;
        acc[1] += bl * w;
    }
    block_reduce_sum<2>(acc);
    if (threadIdx.x == 0) { uo[i] = acc[0] + b[i]; lo[i] = acc[1] + b[i]; }
}

// elementwise analyze_spu
__global__ void k_spu(const float* __restrict__ Uin, const float* __restrict__ Lin, int n,
                      float* __restrict__ us, float* __restrict__ ui,
                      float* __restrict__ ls, float* __restrict__ li,
                      float* __restrict__ nu, float* __restrict__ nl) {
    int i = blockIdx.x * blockDim.x + threadIdx.x;
    if (i >= n) return;
    float ux = Uin[i], lx = Lin[i];
    float uy = spu_f(ux), ly = spu_f(lx);
    float new_ub = fmaxf(uy, ly);
    float sj = (uy - ly) / (ux - lx);
    float ij = uy - sj * ux;
    bool right = lx > 0.f;
    bool left = ux <= 0.f;
    bool crossing = (!left) && (!right);
    float mid = 0.5f * (ux + lx);
    float sp = 2.f * mid, ip = -mid * mid - 0.5f;
    float sm = sigmoidf_(mid);
    float ssm = -sm * (1.f - sm);
    float ism = -sm - ssm * mid;
    float new_lb = crossing ? -0.5f : fminf(uy, ly);
    float spu_s = 2.f * ux, ipu = -ux * ux - 0.5f;
    float limit = spu_s * lx + ipu;
    float clm = (fabsf(lx) > ux) ? 1.f : 0.f;
    float clp = sigmoidf_((clm - 0.5f) * 2.f * SIG_SCALE_C) * (ly - limit) + limit;
    bool ptm = clp < -0.5f;
    float D = 4.f * lx * lx - 4.f * clp - 2.f;
    float x2 = (2.f * lx + sqrtf(fmaxf(D, 0.f))) * 0.5f;
    float spt = 2.f * x2, ipt = -x2 * x2 - 0.5f;
    float sjn = (clp + 0.5f) / lx;   // joining_line(lx,clp, 0,-0.5)
    float ijn = -0.5f;
    float s_cl = ptm ? spt : sjn;
    float i_cl = ptm ? ipt : ijn;
    float sl = sigmoidf_(lx);
    float ssl = -sl * (1.f - sl);
    float isl = -sl - ssl * lx;
    float stv = ssl * ux + isl - uy;
    // binary search
    float Lb = lx, Rb = 0.f;
    #pragma unroll
    for (int t = 0; t < 10; ++t) {
        float mm = 0.5f * (Lb + Rb);
        float smm = sigmoidf_(mm);
        float sms = -smm * (1.f - smm);
        float smi = -smm - sms * mm;
        bool mask = (sms * ux + smi - uy) > 0.f;
        Lb = mask ? mm : Lb;
        Rb = mask ? Rb : mm;
    }
    float scp = sigmoidf_(-SIG_SCALE_C) * (Lb - lx) + lx;
    float sc = sigmoidf_(scp);
    float ssc = -sc * (1.f - sc);
    float isc = -sc - ssc * scp;
    bool up = stv > 0.f;
    float s_cu = up ? ssc : sj;
    float i_cu = up ? isc : ij;
    float usv, uiv, lsv, liv;
    if (right)      { usv = sj;   uiv = ij;   lsv = sp;   liv = ip;   }
    else if (left)  { usv = ssm;  uiv = ism;  lsv = sj;   liv = ij;   }
    else            { usv = s_cu; uiv = i_cu; lsv = s_cl; liv = i_cl; }
    us[i] = usv; ui[i] = uiv; ls[i] = lsv; li[i] = liv;
    nu[i] = new_ub; nl[i] = new_lb;
}

// Builds A (2n x (m+1), stride lda) from W(n x m),b:
//   optional row scale rs/ri (u-rows: rsU/riU, l-rows: rsL/riL)  [diag-SPU init step]
//   optional col mix with (cus,cui,cls,cli)                     [next SPU step]
// u-row r=i:   w = rs*W[i][j]; A = max(w,0)*cus + min(w,0)*cls; inter += max*cui+min*cli
// l-row r=n+i: swapped.  A[r][m] = inter + rs*b[i] + ri
__global__ __launch_bounds__(256) void k_prep(
        const float* __restrict__ W, const float* __restrict__ b,
        int n, int m, int lda,
        const float* __restrict__ rsU, const float* __restrict__ riU,
        const float* __restrict__ rsL, const float* __restrict__ riL,
        const float* __restrict__ cus, const float* __restrict__ cui,
        const float* __restrict__ cls, const float* __restrict__ cli,
        float* __restrict__ A) {
    int r = blockIdx.x;
    bool isU = r < n;
    int i = isU ? r : (r - n);
    const float* Wr = W + (size_t)i * m;
    float rs = 1.f, ri = 0.f;
    if (rsU) { rs = isU ? rsU[i] : rsL[i]; ri = isU ? riU[i] : riL[i]; }
    float* Ar = A + (size_t)r * lda;
    float acc[1] = {0.f};
    if (cus) {
        const float* ps = isU ? cus : cls;
        const float* ns = isU ? cls : cus;
        const float* pi = isU ? cui : cli;
        const float* ni = isU ? cli : cui;
        for (int j = threadIdx.x; j < m; j += 256) {
            float w = rs * Wr[j];
            float pos = fmaxf(w, 0.f), neg = fminf(w, 0.f);
            Ar[j] = pos * ps[j] + neg * ns[j];
            acc[0] += pos * pi[j] + neg * ni[j];
        }
    } else {
        for (int j = threadIdx.x; j < m; j += 256) Ar[j] = rs * Wr[j];
    }
    block_reduce_sum<1>(acc);
    if (threadIdx.x == 0) Ar[m] = acc[0] + rs * b[i] + ri;
}

// mid-chain diag-SPU step: M(2R x (K+1)) -> B(2R x (K+1)), both stride ld
__global__ __launch_bounds__(256) void k_colmix(
        const float* __restrict__ M, float* __restrict__ B,
        int Rhalf, int K, int ld,
        const float* __restrict__ cus, const float* __restrict__ cui,
        const float* __restrict__ cls, const float* __restrict__ cli) {
    int r = blockIdx.x;
    bool isU = r < Rhalf;
    const float* Mr = M + (size_t)r * ld;
    float* Br = B + (size_t)r * ld;
    const float* ps = isU ? cus : cls;
    const float* ns = isU ? cls : cus;
    const float* pi = isU ? cui : cli;
    const float* ni = isU ? cli : cui;
    float acc[1] = {0.f};
    for (int j = threadIdx.x; j < K; j += 256) {
        float w = Mr[j];
        float pos = fmaxf(w, 0.f), neg = fminf(w, 0.f);
        Br[j] = pos * ps[j] + neg * ns[j];
        acc[0] += pos * pi[j] + neg * ni[j];
    }
    block_reduce_sum<1>(acc);
    if (threadIdx.x == 0) Br[K] = Mr[K] + acc[0];
}

// C[r][col] = A[r, 0:K] . bvec + A[r][K]
__global__ __launch_bounds__(256) void k_biascol(
        const float* __restrict__ A, int lda, int K,
        const float* __restrict__ bvec,
        float* __restrict__ C, int ldc, int col) {
    int r = blockIdx.x;
    const float* Ar = A + (size_t)r * lda;
    float acc[1] = {0.f};
    for (int j = threadIdx.x; j < K; j += 256) acc[0] += Ar[j] * bvec[j];
    block_reduce_sum<1>(acc);
    if (threadIdx.x == 0) C[(size_t)r * ldc + col] = acc[0] + Ar[K];
}

// terminal c0 step + combine: u-rows -> U=min(U,v), l-rows -> L=max(L,v)
__global__ __launch_bounds__(256) void k_reduce_c0(
        const float* __restrict__ C, int ldc, int m, int n,
        const float* __restrict__ ubn, const float* __restrict__ lbn,
        float* __restrict__ U, float* __restrict__ L) {
    int r = blockIdx.x;
    bool isU = r < n;
    int i = isU ? r : (r - n);
    const float* Cr = C + (size_t)r * ldc;
    const float* p = isU ? ubn : lbn;
    const float* q = isU ? lbn : ubn;
    float acc[1] = {0.f};
    for (int j = threadIdx.x; j < m; j += 256) {
        float w = Cr[j];
        acc[0] += fmaxf(w, 0.f) * p[j] + fminf(w, 0.f) * q[j];
    }
    block_reduce_sum<1>(acc);
    if (threadIdx.x == 0) {
        float v = acc[0] + Cr[m];
        if (isU) U[i] = fminf(U[i], v);
        else     L[i] = fmaxf(L[i], v);
    }
}

__global__ void k_final_min(const float* __restrict__ l, int n, float* __restrict__ out) {
    float v = 3.4e38f;
    for (int j = threadIdx.x; j < n; j += 64) v = fminf(v, l[j]);
    #pragma unroll
    for (int o = 32; o > 0; o >>= 1) v = fminf(v, __shfl_down(v, o, 64));
    if (threadIdx.x == 0) out[0] = v;
}

// ---------------- tiled fp32 GEMM: C(MxN) = A(MxK) @ B(KxN), row-major ----------------
#define GBM 128
#define GBN 64
#define GBK 16

__global__ __launch_bounds__(256) void k_gemm(
        const float* __restrict__ A, int lda,
        const float* __restrict__ B, int ldb,
        float* __restrict__ C, int ldc,
        int M, int N, int K) {
    __shared__ float As[GBK][GBM];
    __shared__ float Bs[GBK][GBN];
    int tid = threadIdx.x;
    int row0 = blockIdx.y * GBM;
    int col0 = blockIdx.x * GBN;
    int tx = tid & 15;
    int ty = tid >> 4;
    float acc[8][4];
    #pragma unroll
    for (int i = 0; i < 8; ++i)
        #pragma unroll
        for (int j = 0; j < 4; ++j) acc[i][j] = 0.f;

    int arow = tid >> 2;          // 0..63
    int akq = (tid & 3) * 4;      // 0,4,8,12
    int bkrow = tid >> 4;         // 0..15
    int bcq = (tid & 15) * 4;     // 0..60

    for (int kt = 0; kt < K; kt += GBK) {
        #pragma unroll
        for (int p = 0; p < 2; ++p) {
            int r = arow + p * 64;
            int gr = row0 + r;
            float4 v = make_float4(0.f, 0.f, 0.f, 0.f);
            if (gr < M) v = *(const float4*)(A + (size_t)gr * lda + kt + akq);
            As[akq + 0][r] = v.x; As[akq + 1][r] = v.y;
            As[akq + 2][r] = v.z; As[akq + 3][r] = v.w;
        }
        {
            int gc = col0 + bcq;
            float4 v = make_float4(0.f, 0.f, 0.f, 0.f);
            const float* Bp = B + (size_t)(kt + bkrow) * ldb;
            if (gc + 3 < N) v = *(const float4*)(Bp + gc);
            else {
                float t0 = (gc + 0 < N) ? Bp[gc + 0] : 0.f;
                float t1 = (gc + 1 < N) ? Bp[gc + 1] : 0.f;
                float t2 = (gc + 2 < N) ? Bp[gc + 2] : 0.f;
                float t3 = (gc + 3 < N) ? Bp[gc + 3] : 0.f;
                v = make_float4(t0, t1, t2, t3);
            }
            *(float4*)&Bs[bkrow][bcq] = v;
        }
        __syncthreads();
        #pragma unroll
        for (int k = 0; k < GBK; ++k) {
            float4 a0 = *(const float4*)&As[k][ty * 8];
            float4 a1 = *(const float4*)&As[k][ty * 8 + 4];
            float4 b0 = *(const float4*)&Bs[k][tx * 4];
            float am[8] = {a0.x, a0.y, a0.z, a0.w, a1.x, a1.y, a1.z, a1.w};
            float bn[4] = {b0.x, b0.y, b0.z, b0.w};
            #pragma unroll
            for (int i = 0; i < 8; ++i)
                #pragma unroll
                for (int j = 0; j < 4; ++j)
                    acc[i][j] = fmaf(am[i], bn[j], acc[i][j]);
        }
        __syncthreads();
    }
    #pragma unroll
    for (int i = 0; i < 8; ++i) {
        int gr = row0 + ty * 8 + i;
        if (gr >= M) continue;
        int gc = col0 + tx * 4;
        float* Cp = C + (size_t)gr * ldc;
        if (gc + 3 < N) {
            *(float4*)(Cp + gc) = make_float4(acc[i][0], acc[i][1], acc[i][2], acc[i][3]);
        } else {
            #pragma unroll
            for (int j = 0; j < 4; ++j)
                if (gc + j < N) Cp[gc + j] = acc[i][j];
        }
    }
}

// ---------------- host launch ----------------

extern "C" void kernel_launch(void* const* d_in, const int* in_sizes, int n_in,
                              void* d_out, int out_size, void* d_ws, size_t ws_size,
                              hipStream_t stream) {
    (void)in_sizes; (void)n_in; (void)out_size; (void)ws_size;
    const float* x   = (const float*)d_in[0];
    const float* eps = (const float*)d_in[1];
    const float* W1  = (const float*)d_in[2];
    const float* B1  = (const float*)d_in[3];
    const float* W2  = (const float*)d_in[4];
    const float* B2  = (const float*)d_in[5];
    const float* W3  = (const float*)d_in[6];
    const float* B3  = (const float*)d_in[7];
    const float* W4  = (const float*)d_in[8];
    const float* B4  = (const float*)d_in[9];
    float* out = (float*)d_out;

    const int H = 2048, DIN = 784, DOUT = 10;
    const int LDA = 2064;   // stride for 2049-wide buffers (16B aligned rows)
    const int LDN = 800;    // stride for 785-wide buffers

    float* ws = (float*)d_ws;
    size_t off = 0;
    auto alloc = [&](size_t nf) -> float* {
        float* p = ws + off;
        off += (nf + 3) & ~(size_t)3;
        return p;
    };
    float* ubn = alloc(DIN);
    float* lbn = alloc(DIN);
    float* bU1 = alloc(H); float* bL1 = alloc(H);
    float* us1 = alloc(H); float* ui1 = alloc(H); float* ls1 = alloc(H); float* li1 = alloc(H);
    float* pU1 = alloc(H); float* pL1 = alloc(H);
    float* bU2 = alloc(H); float* bL2 = alloc(H);
    float* us2 = alloc(H); float* ui2 = alloc(H); float* ls2 = alloc(H); float* li2 = alloc(H);
    float* pU2 = alloc(H); float* pL2 = alloc(H);
    float* bU3 = alloc(H); float* bL3 = alloc(H);
    float* us3 = alloc(H); float* ui3 = alloc(H); float* ls3 = alloc(H); float* li3 = alloc(H);
    float* pU3 = alloc(H); float* pL3 = alloc(H);
    float* bU4 = alloc(DOUT); float* bL4 = alloc(DOUT);
    float* Abuf = alloc((size_t)2 * H * LDA);
    float* Cbuf = alloc((size_t)2 * H * LDA);

    dim3 blk(256);
    auto gemm = [&](const float* A, int lda, const float* Bm, int ldb,
                    float* C, int ldc, int M, int N, int K) {
        dim3 g((N + GBN - 1) / GBN, (M + GBM - 1) / GBM);
        k_gemm<<<g, blk, 0, stream>>>(A, lda, Bm, ldb, C, ldc, M, N, K);
    };

    // input bounds
    k_input_bounds<<<dim3((DIN + 255) / 256), blk, 0, stream>>>(x, eps, DIN, ubn, lbn);

    // ======== Layer 1 ========
    k_interval_affine<<<dim3(H), blk, 0, stream>>>(W1, B1, ubn, lbn, DIN, bU1, bL1);
    k_spu<<<dim3((H + 255) / 256), blk, 0, stream>>>(bU1, bL1, H, us1, ui1, ls1, li1, pU1, pL1);
    // backsub [c0, c1, s1]: rowscale by s1, no colmix, then c0 reduce
    k_prep<<<dim3(2 * H), blk, 0, stream>>>(W1, B1, H, DIN, LDN,
                                            us1, ui1, ls1, li1,
                                            nullptr, nullptr, nullptr, nullptr, Abuf);
    k_reduce_c0<<<dim3(2 * H), blk, 0, stream>>>(Abuf, LDN, DIN, H, ubn, lbn, pU1, pL1);

    // ======== Layer 2 ========
    k_interval_affine<<<dim3(H), blk, 0, stream>>>(W2, B2, pU1, pL1, H, bU2, bL2);
    // backsub [c0,c1,s1,c2]
    k_prep<<<dim3(2 * H), blk, 0, stream>>>(W2, B2, H, H, LDA,
                                            nullptr, nullptr, nullptr, nullptr,
                                            us1, ui1, ls1, li1, Abuf);
    gemm(Abuf, LDA, W1, DIN, Cbuf, LDN, 2 * H, DIN, H);
    k_biascol<<<dim3(2 * H), blk, 0, stream>>>(Abuf, LDA, H, B1, Cbuf, LDN, DIN);
    k_reduce_c0<<<dim3(2 * H), blk, 0, stream>>>(Cbuf, LDN, DIN, H, ubn, lbn, bU2, bL2);
    k_spu<<<dim3((H + 255) / 256), blk, 0, stream>>>(bU2, bL2, H, us2, ui2, ls2, li2, pU2, pL2);
    // backsub [c0,c1,s1,c2,s2]
    k_prep<<<dim3(2 * H), blk, 0, stream>>>(W2, B2, H, H, LDA,
                                            us2, ui2, ls2, li2,
                                            us1, ui1, ls1, li1, Abuf);
    gemm(Abuf, LDA, W1, DIN, Cbuf, LDN, 2 * H, DIN, H);
    k_biascol<<<dim3(2 * H), blk, 0, stream>>>(Abuf, LDA, H, B1, Cbuf, LDN, DIN);
    k_reduce_c0<<<dim3(2 * H), blk, 0, stream>>>(Cbuf, LDN, DIN, H, ubn, lbn, pU2, pL2);

    // ======== Layer 3 ========
    k_interval_affine<<<dim3(H), blk, 0, stream>>>(W3, B3, pU2, pL2, H, bU3, bL3);
    // backsub [c0,c1,s1,c2,s2,c3]
    k_prep<<<dim3(2 * H), blk, 0, stream>>>(W3, B3, H, H, LDA,
                                            nullptr, nullptr, nullptr, nullptr,
                                            us2, ui2, ls2, li2, Abuf);
    gemm(Abuf, LDA, W2, H, Cbuf, LDA, 2 * H, H, H);
    k_biascol<<<dim3(2 * H), blk, 0, stream>>>(Abuf, LDA, H, B2, Cbuf, LDA, H);
    k_colmix<<<dim3(2 * H), blk, 0, stream>>>(Cbuf, Abuf, H, H, LDA, us1, ui1, ls1, li1);
    gemm(Abuf, LDA, W1, DIN, Cbuf, LDN, 2 * H, DIN, H);
    k_biascol<<<dim3(2 * H), blk, 0, stream>>>(Abuf, LDA, H, B1, Cbuf, LDN, DIN);
    k_reduce_c0<<<dim3(2 * H), blk, 0, stream>>>(Cbuf, LDN, DIN, H, ubn, lbn, bU3, bL3);
    k_spu<<<dim3((H + 255) / 256), blk, 0, stream>>>(bU3, bL3, H, us3, ui3, ls3, li3, pU3, pL3);
    // backsub [c0,c1,s1,c2,s2,c3,s3]
    k_prep<<<dim3(2 * H), blk, 0, stream>>>(W3, B3, H, H, LDA,
                                            us3, ui3, ls3, li3,
                                            us2, ui2, ls2, li2, Abuf);
    gemm(Abuf, LDA, W2, H, Cbuf, LDA, 2 * H, H, H);
    k_biascol<<<dim3(2 * H), blk, 0, stream>>>(Abuf, LDA, H, B2, Cbuf, LDA, H);
    k_colmix<<<dim3(2 * H), blk, 0, stream>>>(Cbuf, Abuf, H, H, LDA, us1, ui1, ls1, li1);
    gemm(Abuf, LDA, W1, DIN, Cbuf, LDN, 2 * H, DIN, H);
    k_biascol<<<dim3(2 * H), blk, 0, stream>>>(Abuf, LDA, H, B1, Cbuf, LDN, DIN);
    k_reduce_c0<<<dim3(2 * H), blk, 0, stream>>>(Cbuf, LDN, DIN, H, ubn, lbn, pU3, pL3);

    // ======== Layer 4 ========
    k_interval_affine<<<dim3(DOUT), blk, 0, stream>>>(W4, B4, pU3, pL3, H, bU4, bL4);
    // backsub [c0,c1,s1,c2,s2,c3,s3,c4]
    k_prep<<<dim3(2 * DOUT), blk, 0, stream>>>(W4, B4, DOUT, H, LDA,
                                               nullptr, nullptr, nullptr, nullptr,
                                               us3, ui3, ls3, li3, Abuf);
    gemm(Abuf, LDA, W3, H, Cbuf, LDA, 2 * DOUT, H, H);
    k_biascol<<<dim3(2 * DOUT), blk, 0, stream>>>(Abuf, LDA, H, B3, Cbuf, LDA, H);
    k_colmix<<<dim3(2 * DOUT), blk, 0, stream>>>(Cbuf, Abuf, DOUT, H, LDA, us2, ui2, ls2, li2);
    gemm(Abuf, LDA, W2, H, Cbuf, LDA, 2 * DOUT, H, H);
    k_biascol<<<dim3(2 * DOUT), blk, 0, stream>>>(Abuf, LDA, H, B2, Cbuf, LDA, H);
    k_colmix<<<dim3(2 * DOUT), blk, 0, stream>>>(Cbuf, Abuf, DOUT, H, LDA, us1, ui1, ls1, li1);
    gemm(Abuf, LDA, W1, DIN, Cbuf, LDN, 2 * DOUT, DIN, H);
    k_biascol<<<dim3(2 * DOUT), blk, 0, stream>>>(Abuf, LDA, H, B1, Cbuf, LDN, DIN);
    k_reduce_c0<<<dim3(2 * DOUT), blk, 0, stream>>>(Cbuf, LDN, DIN, DOUT, ubn, lbn, bU4, bL4);

    k_final_min<<<dim3(1), dim3(64), 0, stream>>>(bL4, DOUT, out);
}

// Round 2
// 878.406 us; speedup vs baseline: 3.4383x; 3.4383x over previous
//
#include <hip/hip_runtime.h>
#include <cstdint>
#include <cstddef>

#define MEAN_C 0.1307f
#define SIGMA_C 0.3081f
#define SIG_SCALE_C 5.0f

typedef __bf16 bf16_t;
typedef __bf16 bf16x8 __attribute__((ext_vector_type(8)));
typedef float f32x4 __attribute__((ext_vector_type(4)));

__device__ __forceinline__ f32x4 mfma16(bf16x8 a, bf16x8 b, f32x4 c) {
    return __builtin_amdgcn_mfma_f32_16x16x32_bf16(a, b, c, 0, 0, 0);
}

// ---------------- device helpers ----------------

__device__ __forceinline__ float sigmoidf_(float x) {
    if (x >= 0.f) { float e = __expf(-x); return 1.f / (1.f + e); }
    float e = __expf(x); return e / (1.f + e);
}

__device__ __forceinline__ float spu_f(float x) {
    return (x >= 0.f) ? (x * x - 0.5f) : (sigmoidf_(-x) - 1.f);
}

// block = 256 threads (4 waves) exactly
template <int NV>
__device__ __forceinline__ void block_reduce_sum(float* v) {
    #pragma unroll
    for (int o = 32; o > 0; o >>= 1) {
        #pragma unroll
        for (int i = 0; i < NV; ++i) v[i] += __shfl_down(v[i], o, 64);
    }
    __shared__ float sh[NV][4];
    int lane = threadIdx.x & 63, wid = threadIdx.x >> 6;
    if (lane == 0) {
        #pragma unroll
        for (int i = 0; i < NV; ++i) sh[i][wid] = v[i];
    }
    __syncthreads();
    if (threadIdx.x == 0) {
        #pragma unroll
        for (int i = 0; i < NV; ++i) v[i] = sh[i][0] + sh[i][1] + sh[i][2] + sh[i][3];
    }
}

// ---------------- small kernels ----------------

__global__ void k_input_bounds(const float* __restrict__ x, const float* __restrict__ eps,
                               int n, float* __restrict__ ubn, float* __restrict__ lbn) {
    int i = blockIdx.x * blockDim.x + threadIdx.x;
    if (i >= n) return;
    float e = eps[0];
    float ub = fminf(x[i] + e, 1.f);
    float lb = fmaxf(x[i] - e, 0.f);
    ubn[i] = (ub - MEAN_C) / SIGMA_C;
    lbn[i] = (lb - MEAN_C) / SIGMA_C;
}

__global__ __launch_bounds__(256) void k_interval_affine(
        const float* __restrict__ W, const float* __restrict__ b,
        const float* __restrict__ U, const float* __restrict__ L,
        int m, float* __restrict__ uo, float* __restrict__ lo) {
    int i = blockIdx.x;
    const float* Wr = W + (size_t)i * m;
    float acc[2] = {0.f, 0.f};
    for (int j = threadIdx.x; j < m; j += 256) {
        float w = Wr[j];
        float uu = U[j], ll = L[j];
        float bu = (w > 0.f) ? uu : ll;
        float bl = (w > 0.f) ? ll : uu;
        acc[0] += bu * w;
        acc[1] += bl * w;
    }
    block_reduce_sum<2>(acc);
    if (threadIdx.x == 0) { uo[i] = acc[0] + b[i]; lo[i] = acc[1] + b[i]; }
}

__global__ void k_spu(const float* __restrict__ Uin, const float* __restrict__ Lin, int n,
                      float* __restrict__ us, float* __restrict__ ui,
                      float* __restrict__ ls, float* __restrict__ li,
                      float* __restrict__ nu, float* __restrict__ nl) {
    int i = blockIdx.x * blockDim.x + threadIdx.x;
    if (i >= n) return;
    float ux = Uin[i], lx = Lin[i];
    float uy = spu_f(ux), ly = spu_f(lx);
    float new_ub = fmaxf(uy, ly);
    float sj = (uy - ly) / (ux - lx);
    float ij = uy - sj * ux;
    bool right = lx > 0.f;
    bool left = ux <= 0.f;
    bool crossing = (!left) && (!right);
    float mid = 0.5f * (ux + lx);
    float sp = 2.f * mid, ip = -mid * mid - 0.5f;
    float sm = sigmoidf_(mid);
    float ssm = -sm * (1.f - sm);
    float ism = -sm - ssm * mid;
    float new_lb = crossing ? -0.5f : fminf(uy, ly);
    float spu_s = 2.f * ux, ipu = -ux * ux - 0.5f;
    float limit = spu_s * lx + ipu;
    float clm = (fabsf(lx) > ux) ? 1.f : 0.f;
    float clp = sigmoidf_((clm - 0.5f) * 2.f * SIG_SCALE_C) * (ly - limit) + limit;
    bool ptm = clp < -0.5f;
    float D = 4.f * lx * lx - 4.f * clp - 2.f;
    float x2 = (2.f * lx + sqrtf(fmaxf(D, 0.f))) * 0.5f;
    float spt = 2.f * x2, ipt = -x2 * x2 - 0.5f;
    float sjn = (clp + 0.5f) / lx;
    float ijn = -0.5f;
    float s_cl = ptm ? spt : sjn;
    float i_cl = ptm ? ipt : ijn;
    float sl = sigmoidf_(lx);
    float ssl = -sl * (1.f - sl);
    float isl = -sl - ssl * lx;
    float stv = ssl * ux + isl - uy;
    float Lb = lx, Rb = 0.f;
    #pragma unroll
    for (int t = 0; t < 10; ++t) {
        float mm = 0.5f * (Lb + Rb);
        float smm = sigmoidf_(mm);
        float sms = -smm * (1.f - smm);
        float smi = -smm - sms * mm;
        bool mask = (sms * ux + smi - uy) > 0.f;
        Lb = mask ? mm : Lb;
        Rb = mask ? Rb : mm;
    }
    float scp = sigmoidf_(-SIG_SCALE_C) * (Lb - lx) + lx;
    float sc = sigmoidf_(scp);
    float ssc = -sc * (1.f - sc);
    float isc = -sc - ssc * scp;
    bool up = stv > 0.f;
    float s_cu = up ? ssc : sj;
    float i_cu = up ? isc : ij;
    float usv, uiv, lsv, liv;
    if (right)      { usv = sj;   uiv = ij;   lsv = sp;   liv = ip;   }
    else if (left)  { usv = ssm;  uiv = ism;  lsv = sj;   liv = ij;   }
    else            { usv = s_cu; uiv = i_cu; lsv = s_cl; liv = i_cl; }
    us[i] = usv; ui[i] = uiv; ls[i] = lsv; li[i] = liv;
    nu[i] = new_ub; nl[i] = new_lb;
}

// ---------------- fp32 path (layer 1 only) ----------------

__global__ __launch_bounds__(256) void k_prep(
        const float* __restrict__ W, const float* __restrict__ b,
        int n, int m, int lda,
        const float* __restrict__ rsU, const float* __restrict__ riU,
        const float* __restrict__ rsL, const float* __restrict__ riL,
        float* __restrict__ A) {
    int r = blockIdx.x;
    bool isU = r < n;
    int i = isU ? r : (r - n);
    const float* Wr = W + (size_t)i * m;
    float rs = isU ? rsU[i] : rsL[i];
    float ri = isU ? riU[i] : riL[i];
    float* Ar = A + (size_t)r * lda;
    for (int j = threadIdx.x; j < m; j += 256) Ar[j] = rs * Wr[j];
    if (threadIdx.x == 0) Ar[m] = rs * b[i] + ri;
}

__global__ __launch_bounds__(256) void k_reduce_c0(
        const float* __restrict__ C, int ldc, int m, int n,
        const float* __restrict__ ubn, const float* __restrict__ lbn,
        float* __restrict__ U, float* __restrict__ L) {
    int r = blockIdx.x;
    bool isU = r < n;
    int i = isU ? r : (r - n);
    const float* Cr = C + (size_t)r * ldc;
    const float* p = isU ? ubn : lbn;
    const float* q = isU ? lbn : ubn;
    float acc[1] = {0.f};
    for (int j = threadIdx.x; j < m; j += 256) {
        float w = Cr[j];
        acc[0] += fmaxf(w, 0.f) * p[j] + fminf(w, 0.f) * q[j];
    }
    block_reduce_sum<1>(acc);
    if (threadIdx.x == 0) {
        float v = acc[0] + Cr[m];
        if (isU) U[i] = fminf(U[i], v);
        else     L[i] = fmaxf(L[i], v);
    }
}

// ---------------- bf16 path ----------------

// transpose + convert: W (K x N real, ldw) fp32 -> Wt (Npad x K) bf16, zero-pad n >= N
__global__ __launch_bounds__(256) void k_wT(
        const float* __restrict__ W, int N, int ldw,
        bf16_t* __restrict__ Wt, int ldt) {
    __shared__ bf16_t t[64][72];
    int k0 = blockIdx.x * 64, n0 = blockIdx.y * 64;
    int tid = threadIdx.x;
    int r = tid >> 2;
    int c0 = (tid & 3) * 16;
    const float* Wr = W + (size_t)(k0 + r) * ldw;
    #pragma unroll
    for (int c = 0; c < 16; ++c) {
        int gn = n0 + c0 + c;
        float vv = (gn < N) ? Wr[gn] : 0.f;
        t[c0 + c][r] = (bf16_t)vv;
    }
    __syncthreads();
    bf16_t* o = Wt + (size_t)(n0 + r) * ldt + k0 + c0;
    bf16x8 v0, v1;
    #pragma unroll
    for (int u = 0; u < 8; ++u) { v0[u] = t[r][c0 + u]; v1[u] = t[r][c0 + 8 + u]; }
    *(bf16x8*)o = v0;
    *(bf16x8*)(o + 8) = v1;
}

// prep into bf16 Ab (row-major, ld = 2048) + fp32 bias vector av.
// grid = Mpad rows; rows >= 2n are zeroed. m fixed at 2048 (one j per thread x8).
__global__ __launch_bounds__(256) void k_prep16(
        const float* __restrict__ W, const float* __restrict__ b, int n,
        const float* __restrict__ rsU, const float* __restrict__ riU,
        const float* __restrict__ rsL, const float* __restrict__ riL,
        const float* __restrict__ cus, const float* __restrict__ cui,
        const float* __restrict__ cls, const float* __restrict__ cli,
        bf16_t* __restrict__ Ab, float* __restrict__ av) {
    int r = blockIdx.x;
    bf16_t* Ar = Ab + (size_t)r * 2048;
    int j0 = threadIdx.x * 8;
    if (r >= 2 * n) {
        bf16x8 z;
        #pragma unroll
        for (int u = 0; u < 8; ++u) z[u] = (bf16_t)0.f;
        *(bf16x8*)(Ar + j0) = z;
        if (threadIdx.x == 0) av[r] = 0.f;
        return;
    }
    bool isU = r < n;
    int i = isU ? r : (r - n);
    const float* Wr = W + (size_t)i * 2048;
    float rs = 1.f, ri = 0.f;
    if (rsU) { rs = isU ? rsU[i] : rsL[i]; ri = isU ? riU[i] : riL[i]; }
    const float* ps = isU ? cus : cls;
    const float* ns = isU ? cls : cus;
    const float* pi = isU ? cui : cli;
    const float* ni = isU ? cli : cui;
    float a = 0.f;
    bf16x8 v;
    #pragma unroll
    for (int u = 0; u < 8; ++u) {
        float w = rs * Wr[j0 + u];
        float pos = fmaxf(w, 0.f), neg = fminf(w, 0.f);
        v[u] = (bf16_t)(pos * ps[j0 + u] + neg * ns[j0 + u]);
        a += pos * pi[j0 + u] + neg * ni[j0 + u];
    }
    *(bf16x8*)(Ar + j0) = v;
    float acc[1] = {a};
    block_reduce_sum<1>(acc);
    if (threadIdx.x == 0) av[r] = acc[0] + rs * b[i] + ri;
}

// diag-SPU step: Cb fp32 (Mpad x 2048, ldc) -> Ab bf16, av += intercept dot
__global__ __launch_bounds__(256) void k_colmix16(
        const float* __restrict__ Cb, int ldc, int Rhalf,
        const float* __restrict__ cus, const float* __restrict__ cui,
        const float* __restrict__ cls, const float* __restrict__ cli,
        bf16_t* __restrict__ Ab, float* __restrict__ av) {
    int r = blockIdx.x;
    bool isU = r < Rhalf;
    const float* Cr = Cb + (size_t)r * ldc;
    bf16_t* Ar = Ab + (size_t)r * 2048;
    const float* ps = isU ? cus : cls;
    const float* ns = isU ? cls : cus;
    const float* pi = isU ? cui : cli;
    const float* ni = isU ? cli : cui;
    int j0 = threadIdx.x * 8;
    float a = 0.f;
    bf16x8 v;
    #pragma unroll
    for (int u = 0; u < 8; ++u) {
        float w = Cr[j0 + u];
        float pos = fmaxf(w, 0.f), neg = fminf(w, 0.f);
        v[u] = (bf16_t)(pos * ps[j0 + u] + neg * ns[j0 + u]);
        a += pos * pi[j0 + u] + neg * ni[j0 + u];
    }
    *(bf16x8*)(Ar + j0) = v;
    float acc[1] = {a};
    block_reduce_sum<1>(acc);
    if (threadIdx.x == 0) av[r] += acc[0];
}

// av[r] += dot(Ab[r, 0:2048], bvec)
__global__ __launch_bounds__(256) void k_biascol16(
        const bf16_t* __restrict__ Ab, const float* __restrict__ bvec,
        float* __restrict__ av) {
    int r = blockIdx.x;
    const bf16_t* Ar = Ab + (size_t)r * 2048;
    int j0 = threadIdx.x * 8;
    bf16x8 v = *(const bf16x8*)(Ar + j0);
    float a = 0.f;
    #pragma unroll
    for (int u = 0; u < 8; ++u) a += (float)v[u] * bvec[j0 + u];
    float acc[1] = {a};
    block_reduce_sum<1>(acc);
    if (threadIdx.x == 0) av[r] += acc[0];
}

// final c0 step: Cb fp32 (rows x ldc, cols 0..m-1) + av -> U=min(U,v) / L=max(L,v)
__global__ __launch_bounds__(256) void k_reduce16(
        const float* __restrict__ Cb, int ldc, int m, int n,
        const float* __restrict__ av,
        const float* __restrict__ ubn, const float* __restrict__ lbn,
        float* __restrict__ U, float* __restrict__ L) {
    int r = blockIdx.x;
    bool isU = r < n;
    int i = isU ? r : (r - n);
    const float* Cr = Cb + (size_t)r * ldc;
    const float* p = isU ? ubn : lbn;
    const float* q = isU ? lbn : ubn;
    float acc[1] = {0.f};
    for (int j = threadIdx.x; j < m; j += 256) {
        float w = Cr[j];
        acc[0] += fmaxf(w, 0.f) * p[j] + fminf(w, 0.f) * q[j];
    }
    block_reduce_sum<1>(acc);
    if (threadIdx.x == 0) {
        float v = acc[0] + av[r];
        if (isU) U[i] = fminf(U[i], v);
        else     L[i] = fmaxf(L[i], v);
    }
}

__global__ void k_final_min(const float* __restrict__ l, int n, float* __restrict__ out) {
    float v = 3.4e38f;
    for (int j = threadIdx.x; j < n; j += 64) v = fminf(v, l[j]);
    #pragma unroll
    for (int o = 32; o > 0; o >>= 1) v = fminf(v, __shfl_down(v, o, 64));
    if (threadIdx.x == 0) out[0] = v;
}

// ---------------- bf16 MFMA GEMM ----------------
// C (fp32, ldc) = A (M x K bf16, ld=K) @ Bt^T  where Bt is (N x K bf16, ld=K).
// Tiles: 128x128x32, 4 waves, each wave 64x64 via 4x4 mfma_f32_16x16x32_bf16.
// LDS chunk layout: chunk c = t*64 + q*16 + m  (16 bytes each) so both staging
// writes and fragment reads are lane-linear (conflict-free ds_*_b128).
__global__ __launch_bounds__(256) void k_gemm16(
        const bf16_t* __restrict__ A, const bf16_t* __restrict__ Bt,
        float* __restrict__ C, int ldc, int K) {
    __shared__ __align__(16) bf16_t As[128 * 32];
    __shared__ __align__(16) bf16_t Bs[128 * 32];
    int tid = threadIdx.x;
    int lane = tid & 63, w = tid >> 6;
    int wm = w & 1, wn = w >> 1;
    size_t row0 = (size_t)blockIdx.y * 128;
    size_t col0 = (size_t)blockIdx.x * 128;

    f32x4 acc[4][4];
    #pragma unroll
    for (int i = 0; i < 4; ++i)
        #pragma unroll
        for (int j = 0; j < 4; ++j) acc[i][j] = (f32x4){0.f, 0.f, 0.f, 0.f};

    int c1 = tid, c2 = tid + 256;
    int t1 = c1 >> 6, q1 = (c1 >> 4) & 3, m1 = c1 & 15;
    int t2 = c2 >> 6, q2 = (c2 >> 4) & 3, m2 = c2 & 15;
    const bf16_t* a1 = A + (row0 + t1 * 16 + m1) * (size_t)K + q1 * 8;
    const bf16_t* a2 = A + (row0 + t2 * 16 + m2) * (size_t)K + q2 * 8;
    const bf16_t* b1 = Bt + (col0 + t1 * 16 + m1) * (size_t)K + q1 * 8;
    const bf16_t* b2 = Bt + (col0 + t2 * 16 + m2) * (size_t)K + q2 * 8;

    for (int kt = 0; kt < K; kt += 32) {
        *(bf16x8*)(&As[c1 * 8]) = *(const bf16x8*)(a1 + kt);
        *(bf16x8*)(&As[c2 * 8]) = *(const bf16x8*)(a2 + kt);
        *(bf16x8*)(&Bs[c1 * 8]) = *(const bf16x8*)(b1 + kt);
        *(bf16x8*)(&Bs[c2 * 8]) = *(const bf16x8*)(b2 + kt);
        __syncthreads();
        bf16x8 af[4], bfr[4];
        #pragma unroll
        for (int i = 0; i < 4; ++i)
            af[i] = *(const bf16x8*)(&As[(wm * 4 + i) * 512 + lane * 8]);
        #pragma unroll
        for (int j = 0; j < 4; ++j)
            bfr[j] = *(const bf16x8*)(&Bs[(wn * 4 + j) * 512 + lane * 8]);
        #pragma unroll
        for (int i = 0; i < 4; ++i)
            #pragma unroll
            for (int j = 0; j < 4; ++j)
                acc[i][j] = mfma16(af[i], bfr[j], acc[i][j]);
        __syncthreads();
    }
    // C/D layout: col = lane&15, row = (lane>>4)*4 + reg
    int cq = lane >> 4, cn = lane & 15;
    #pragma unroll
    for (int i = 0; i < 4; ++i) {
        size_t gr0 = row0 + wm * 64 + i * 16 + cq * 4;
        #pragma unroll
        for (int j = 0; j < 4; ++j) {
            size_t gc = col0 + wn * 64 + j * 16 + cn;
            #pragma unroll
            for (int rg = 0; rg < 4; ++rg)
                C[(gr0 + rg) * (size_t)ldc + gc] = acc[i][j][rg];
        }
    }
}

// ---------------- host launch ----------------

extern "C" void kernel_launch(void* const* d_in, const int* in_sizes, int n_in,
                              void* d_out, int out_size, void* d_ws, size_t ws_size,
                              hipStream_t stream) {
    (void)in_sizes; (void)n_in; (void)out_size; (void)ws_size;
    const float* x   = (const float*)d_in[0];
    const float* eps = (const float*)d_in[1];
    const float* W1  = (const float*)d_in[2];
    const float* B1  = (const float*)d_in[3];
    const float* W2  = (const float*)d_in[4];
    const float* B2  = (const float*)d_in[5];
    const float* W3  = (const float*)d_in[6];
    const float* B3  = (const float*)d_in[7];
    const float* W4  = (const float*)d_in[8];
    const float* B4  = (const float*)d_in[9];
    float* out = (float*)d_out;

    const int H = 2048, DIN = 784, DOUT = 10;
    const int NP1 = 896;           // DIN padded to x128
    const int LDN = 800;           // fp32 layer-1 stride (784 cols + bias col)

    float* ws = (float*)d_ws;
    size_t off = 0;
    auto alloc = [&](size_t nf) -> float* {
        float* p = ws + off;
        off += (nf + 3) & ~(size_t)3;
        return p;
    };
    float* ubn = alloc(DIN);
    float* lbn = alloc(DIN);
    float* bU1 = alloc(H); float* bL1 = alloc(H);
    float* us1 = alloc(H); float* ui1 = alloc(H); float* ls1 = alloc(H); float* li1 = alloc(H);
    float* pU1 = alloc(H); float* pL1 = alloc(H);
    float* bU2 = alloc(H); float* bL2 = alloc(H);
    float* us2 = alloc(H); float* ui2 = alloc(H); float* ls2 = alloc(H); float* li2 = alloc(H);
    float* pU2 = alloc(H); float* pL2 = alloc(H);
    float* bU3 = alloc(H); float* bL3 = alloc(H);
    float* us3 = alloc(H); float* ui3 = alloc(H); float* ls3 = alloc(H); float* li3 = alloc(H);
    float* pU3 = alloc(H); float* pL3 = alloc(H);
    float* bU4 = alloc(32); float* bL4 = alloc(32);
    float* av  = alloc(2 * H);
    bf16_t* Ab  = (bf16_t*)alloc((size_t)2 * H * H / 2);       // 4096 x 2048 bf16
    bf16_t* W1t = (bf16_t*)alloc((size_t)NP1 * H / 2);         // 896 x 2048 bf16
    bf16_t* W2t = (bf16_t*)alloc((size_t)H * H / 2);           // 2048 x 2048 bf16
    bf16_t* W3t = (bf16_t*)alloc((size_t)H * H / 2);
    float* Cb = alloc((size_t)2 * H * H);                      // 4096 x 2048 fp32 (32 MB)
    float* A32 = Cb;                                           // layer-1 fp32 scratch aliases Cb

    dim3 blk(256);
    auto gemm = [&](const bf16_t* A, const bf16_t* Bt, float* C, int N, int Mpad) {
        dim3 g(N / 128, Mpad / 128);
        k_gemm16<<<g, blk, 0, stream>>>(A, Bt, C, N, H);
    };

    // weight transpose/convert (independent of bound chain)
    k_wT<<<dim3(H / 64, NP1 / 64), blk, 0, stream>>>(W1, DIN, DIN, W1t, H);
    k_wT<<<dim3(H / 64, H / 64), blk, 0, stream>>>(W2, H, H, W2t, H);
    k_wT<<<dim3(H / 64, H / 64), blk, 0, stream>>>(W3, H, H, W3t, H);

    k_input_bounds<<<dim3((DIN + 255) / 256), blk, 0, stream>>>(x, eps, DIN, ubn, lbn);

    // ======== Layer 1 (fp32 exact) ========
    k_interval_affine<<<dim3(H), blk, 0, stream>>>(W1, B1, ubn, lbn, DIN, bU1, bL1);
    k_spu<<<dim3(H / 256), blk, 0, stream>>>(bU1, bL1, H, us1, ui1, ls1, li1, pU1, pL1);
    k_prep<<<dim3(2 * H), blk, 0, stream>>>(W1, B1, H, DIN, LDN, us1, ui1, ls1, li1, A32);
    k_reduce_c0<<<dim3(2 * H), blk, 0, stream>>>(A32, LDN, DIN, H, ubn, lbn, pU1, pL1);

    // ======== Layer 2 ========
    k_interval_affine<<<dim3(H), blk, 0, stream>>>(W2, B2, pU1, pL1, H, bU2, bL2);
    k_prep16<<<dim3(2 * H), blk, 0, stream>>>(W2, B2, H,
        nullptr, nullptr, nullptr, nullptr, us1, ui1, ls1, li1, Ab, av);
    gemm(Ab, W1t, Cb, NP1, 2 * H);
    k_biascol16<<<dim3(2 * H), blk, 0, stream>>>(Ab, B1, av);
    k_reduce16<<<dim3(2 * H), blk, 0, stream>>>(Cb, NP1, DIN, H, av, ubn, lbn, bU2, bL2);
    k_spu<<<dim3(H / 256), blk, 0, stream>>>(bU2, bL2, H, us2, ui2, ls2, li2, pU2, pL2);
    k_prep16<<<dim3(2 * H), blk, 0, stream>>>(W2, B2, H,
        us2, ui2, ls2, li2, us1, ui1, ls1, li1, Ab, av);
    gemm(Ab, W1t, Cb, NP1, 2 * H);
    k_biascol16<<<dim3(2 * H), blk, 0, stream>>>(Ab, B1, av);
    k_reduce16<<<dim3(2 * H), blk, 0, stream>>>(Cb, NP1, DIN, H, av, ubn, lbn, pU2, pL2);

    // ======== Layer 3 ========
    k_interval_affine<<<dim3(H), blk, 0, stream>>>(W3, B3, pU2, pL2, H, bU3, bL3);
    k_prep16<<<dim3(2 * H), blk, 0, stream>>>(W3, B3, H,
        nullptr, nullptr, nullptr, nullptr, us2, ui2, ls2, li2, Ab, av);
    gemm(Ab, W2t, Cb, H, 2 * H);
    k_biascol16<<<dim3(2 * H), blk, 0, stream>>>(Ab, B2, av);
    k_colmix16<<<dim3(2 * H), blk, 0, stream>>>(Cb, H, H, us1, ui1, ls1, li1, Ab, av);
    gemm(Ab, W1t, Cb, NP1, 2 * H);
    k_biascol16<<<dim3(2 * H), blk, 0, stream>>>(Ab, B1, av);
    k_reduce16<<<dim3(2 * H), blk, 0, stream>>>(Cb, NP1, DIN, H, av, ubn, lbn, bU3, bL3);
    k_spu<<<dim3(H / 256), blk, 0, stream>>>(bU3, bL3, H, us3, ui3, ls3, li3, pU3, pL3);
    k_prep16<<<dim3(2 * H), blk, 0, stream>>>(W3, B3, H,
        us3, ui3, ls3, li3, us2, ui2, ls2, li2, Ab, av);
    gemm(Ab, W2t, Cb, H, 2 * H);
    k_biascol16<<<dim3(2 * H), blk, 0, stream>>>(Ab, B2, av);
    k_colmix16<<<dim3(2 * H), blk, 0, stream>>>(Cb, H, H, us1, ui1, ls1, li1, Ab, av);
    gemm(Ab, W1t, Cb, NP1, 2 * H);
    k_biascol16<<<dim3(2 * H), blk, 0, stream>>>(Ab, B1, av);
    k_reduce16<<<dim3(2 * H), blk, 0, stream>>>(Cb, NP1, DIN, H, av, ubn, lbn, pU3, pL3);

    // ======== Layer 4 (M = 20 padded to 128) ========
    const int MP4 = 128;
    k_interval_affine<<<dim3(DOUT), blk, 0, stream>>>(W4, B4, pU3, pL3, H, bU4, bL4);
    k_prep16<<<dim3(MP4), blk, 0, stream>>>(W4, B4, DOUT,
        nullptr, nullptr, nullptr, nullptr, us3, ui3, ls3, li3, Ab, av);
    gemm(Ab, W3t, Cb, H, MP4);
    k_biascol16<<<dim3(MP4), blk, 0, stream>>>(Ab, B3, av);
    k_colmix16<<<dim3(MP4), blk, 0, stream>>>(Cb, H, DOUT, us2, ui2, ls2, li2, Ab, av);
    gemm(Ab, W2t, Cb, H, MP4);
    k_biascol16<<<dim3(MP4), blk, 0, stream>>>(Ab, B2, av);
    k_colmix16<<<dim3(MP4), blk, 0, stream>>>(Cb, H, DOUT, us1, ui1, ls1, li1, Ab, av);
    gemm(Ab, W1t, Cb, NP1, MP4);
    k_biascol16<<<dim3(MP4), blk, 0, stream>>>(Ab, B1, av);
    k_reduce16<<<dim3(2 * DOUT), blk, 0, stream>>>(Cb, NP1, DIN, DOUT, av, ubn, lbn, bU4, bL4);

    k_final_min<<<dim3(1), dim3(64), 0, stream>>>(bL4, DOUT, out);
}

// Round 3
// 806.577 us; speedup vs baseline: 3.7445x; 1.0891x over previous
//
#include <hip/hip_runtime.h>
#include <cstdint>
#include <cstddef>

#define MEAN_C 0.1307f
#define SIGMA_C 0.3081f
#define SIG_SCALE_C 5.0f

typedef __bf16 bf16_t;
typedef __bf16 bf16x8 __attribute__((ext_vector_type(8)));
typedef float f32x4 __attribute__((ext_vector_type(4)));

__device__ __forceinline__ f32x4 mfma16(bf16x8 a, bf16x8 b, f32x4 c) {
    return __builtin_amdgcn_mfma_f32_16x16x32_bf16(a, b, c, 0, 0, 0);
}

typedef const __attribute__((address_space(1))) void* gvp;
typedef __attribute__((address_space(3))) void* lvp;
__device__ __forceinline__ void g2l16(const void* g, void* l) {
    __builtin_amdgcn_global_load_lds((gvp)g, (lvp)l, 16, 0, 0);
}

// swizzled bf16 operand layout: 16x32 tiles (1KB), chunk q*16+m (16B), elem k&7
// offset(r,k) for K = ktiles*32 cols
__device__ __forceinline__ size_t swz(int r, int k, int ktiles) {
    return (((size_t)(r >> 4) * ktiles + (k >> 5)) << 9)
         + (((k >> 3) & 3) << 7) + ((r & 15) << 3) + (k & 7);
}

// ---------------- device helpers ----------------

__device__ __forceinline__ float sigmoidf_(float x) {
    if (x >= 0.f) { float e = __expf(-x); return 1.f / (1.f + e); }
    float e = __expf(x); return e / (1.f + e);
}

__device__ __forceinline__ float spu_f(float x) {
    return (x >= 0.f) ? (x * x - 0.5f) : (sigmoidf_(-x) - 1.f);
}

template <int NV>
__device__ __forceinline__ void block_reduce_sum(float* v) {
    #pragma unroll
    for (int o = 32; o > 0; o >>= 1) {
        #pragma unroll
        for (int i = 0; i < NV; ++i) v[i] += __shfl_down(v[i], o, 64);
    }
    __shared__ float sh[NV][4];
    int lane = threadIdx.x & 63, wid = threadIdx.x >> 6;
    if (lane == 0) {
        #pragma unroll
        for (int i = 0; i < NV; ++i) sh[i][wid] = v[i];
    }
    __syncthreads();
    if (threadIdx.x == 0) {
        #pragma unroll
        for (int i = 0; i < NV; ++i) v[i] = sh[i][0] + sh[i][1] + sh[i][2] + sh[i][3];
    }
}

// ---------------- small kernels ----------------

__global__ void k_input_bounds(const float* __restrict__ x, const float* __restrict__ eps,
                               int n, float* __restrict__ ubn, float* __restrict__ lbn) {
    int i = blockIdx.x * blockDim.x + threadIdx.x;
    if (i >= n) return;
    float e = eps[0];
    float ub = fminf(x[i] + e, 1.f);
    float lb = fmaxf(x[i] - e, 0.f);
    ubn[i] = (ub - MEAN_C) / SIGMA_C;
    lbn[i] = (lb - MEAN_C) / SIGMA_C;
}

__global__ __launch_bounds__(256) void k_interval_affine(
        const float* __restrict__ W, const float* __restrict__ b,
        const float* __restrict__ U, const float* __restrict__ L,
        int m, float* __restrict__ uo, float* __restrict__ lo) {
    int i = blockIdx.x;
    const float* Wr = W + (size_t)i * m;
    float acc[2] = {0.f, 0.f};
    for (int j = threadIdx.x; j < m; j += 256) {
        float w = Wr[j];
        float uu = U[j], ll = L[j];
        float bu = (w > 0.f) ? uu : ll;
        float bl = (w > 0.f) ? ll : uu;
        acc[0] += bu * w;
        acc[1] += bl * w;
    }
    block_reduce_sum<2>(acc);
    if (threadIdx.x == 0) { uo[i] = acc[0] + b[i]; lo[i] = acc[1] + b[i]; }
}

__global__ void k_spu(const float* __restrict__ Uin, const float* __restrict__ Lin, int n,
                      float* __restrict__ us, float* __restrict__ ui,
                      float* __restrict__ ls, float* __restrict__ li,
                      float* __restrict__ nu, float* __restrict__ nl) {
    int i = blockIdx.x * blockDim.x + threadIdx.x;
    if (i >= n) return;
    float ux = Uin[i], lx = Lin[i];
    float uy = spu_f(ux), ly = spu_f(lx);
    float new_ub = fmaxf(uy, ly);
    float sj = (uy - ly) / (ux - lx);
    float ij = uy - sj * ux;
    bool right = lx > 0.f;
    bool left = ux <= 0.f;
    bool crossing = (!left) && (!right);
    float mid = 0.5f * (ux + lx);
    float sp = 2.f * mid, ip = -mid * mid - 0.5f;
    float sm = sigmoidf_(mid);
    float ssm = -sm * (1.f - sm);
    float ism = -sm - ssm * mid;
    float new_lb = crossing ? -0.5f : fminf(uy, ly);
    float spu_s = 2.f * ux, ipu = -ux * ux - 0.5f;
    float limit = spu_s * lx + ipu;
    float clm = (fabsf(lx) > ux) ? 1.f : 0.f;
    float clp = sigmoidf_((clm - 0.5f) * 2.f * SIG_SCALE_C) * (ly - limit) + limit;
    bool ptm = clp < -0.5f;
    float D = 4.f * lx * lx - 4.f * clp - 2.f;
    float x2 = (2.f * lx + sqrtf(fmaxf(D, 0.f))) * 0.5f;
    float spt = 2.f * x2, ipt = -x2 * x2 - 0.5f;
    float sjn = (clp + 0.5f) / lx;
    float ijn = -0.5f;
    float s_cl = ptm ? spt : sjn;
    float i_cl = ptm ? ipt : ijn;
    float sl = sigmoidf_(lx);
    float ssl = -sl * (1.f - sl);
    float isl = -sl - ssl * lx;
    float stv = ssl * ux + isl - uy;
    float Lb = lx, Rb = 0.f;
    #pragma unroll
    for (int t = 0; t < 10; ++t) {
        float mm = 0.5f * (Lb + Rb);
        float smm = sigmoidf_(mm);
        float sms = -smm * (1.f - smm);
        float smi = -smm - sms * mm;
        bool mask = (sms * ux + smi - uy) > 0.f;
        Lb = mask ? mm : Lb;
        Rb = mask ? Rb : mm;
    }
    float scp = sigmoidf_(-SIG_SCALE_C) * (Lb - lx) + lx;
    float sc = sigmoidf_(scp);
    float ssc = -sc * (1.f - sc);
    float isc = -sc - ssc * scp;
    bool up = stv > 0.f;
    float s_cu = up ? ssc : sj;
    float i_cu = up ? isc : ij;
    float usv, uiv, lsv, liv;
    if (right)      { usv = sj;   uiv = ij;   lsv = sp;   liv = ip;   }
    else if (left)  { usv = ssm;  uiv = ism;  lsv = sj;   liv = ij;   }
    else            { usv = s_cu; uiv = i_cu; lsv = s_cl; liv = i_cl; }
    us[i] = usv; ui[i] = uiv; ls[i] = lsv; li[i] = liv;
    nu[i] = new_ub; nl[i] = new_lb;
}

// ---------------- fp32 path (layer 1 only) ----------------

__global__ __launch_bounds__(256) void k_prep(
        const float* __restrict__ W, const float* __restrict__ b,
        int n, int m, int lda,
        const float* __restrict__ rsU, const float* __restrict__ riU,
        const float* __restrict__ rsL, const float* __restrict__ riL,
        float* __restrict__ A) {
    int r = blockIdx.x;
    bool isU = r < n;
    int i = isU ? r : (r - n);
    const float* Wr = W + (size_t)i * m;
    float rs = isU ? rsU[i] : rsL[i];
    float ri = isU ? riU[i] : riL[i];
    float* Ar = A + (size_t)r * lda;
    for (int j = threadIdx.x; j < m; j += 256) Ar[j] = rs * Wr[j];
    if (threadIdx.x == 0) Ar[m] = rs * b[i] + ri;
}

__global__ __launch_bounds__(256) void k_reduce_c0(
        const float* __restrict__ C, int ldc, int m, int n,
        const float* __restrict__ ubn, const float* __restrict__ lbn,
        float* __restrict__ U, float* __restrict__ L) {
    int r = blockIdx.x;
    bool isU = r < n;
    int i = isU ? r : (r - n);
    const float* Cr = C + (size_t)r * ldc;
    const float* p = isU ? ubn : lbn;
    const float* q = isU ? lbn : ubn;
    float acc[1] = {0.f};
    for (int j = threadIdx.x; j < m; j += 256) {
        float w = Cr[j];
        acc[0] += fmaxf(w, 0.f) * p[j] + fminf(w, 0.f) * q[j];
    }
    block_reduce_sum<1>(acc);
    if (threadIdx.x == 0) {
        float v = acc[0] + Cr[m];
        if (isU) U[i] = fminf(U[i], v);
        else     L[i] = fmaxf(L[i], v);
    }
}

// ---------------- bf16 path (all operands in swizzled layout, K=2048) ----------------

#define KTILES 64   // 2048 / 32

// transpose + convert + swizzle: W (K x N real, ldw) fp32 -> Wt swizzled (Npad x K) bf16
__global__ __launch_bounds__(256) void k_wT(
        const float* __restrict__ W, int N, int ldw,
        bf16_t* __restrict__ Wt) {
    __shared__ bf16_t t[64][72];
    int k0 = blockIdx.x * 64, n0 = blockIdx.y * 64;
    int tid = threadIdx.x;
    int r = tid >> 2;
    int c0 = (tid & 3) * 16;
    const float* Wr = W + (size_t)(k0 + r) * ldw;
    #pragma unroll
    for (int c = 0; c < 16; ++c) {
        int gn = n0 + c0 + c;
        float vv = (gn < N) ? Wr[gn] : 0.f;
        t[c0 + c][r] = (bf16_t)vv;
    }
    __syncthreads();
    #pragma unroll
    for (int p = 0; p < 2; ++p) {
        int c = tid + p * 256;
        int lr = c & 63, lq = c >> 6;
        bf16x8 v;
        #pragma unroll
        for (int u = 0; u < 8; ++u) v[u] = t[lr][lq * 8 + u];
        *(bf16x8*)(Wt + swz(n0 + lr, k0 + lq * 8, KTILES)) = v;
    }
}

// prep into swizzled bf16 Ab + fp32 bias vector av (fused biascol: av gets
// intercept dot + mixed-row . bvec + rs*b + ri). grid = Mpad rows; rows >= 2n zeroed.
__global__ __launch_bounds__(256) void k_prep16(
        const float* __restrict__ W, const float* __restrict__ b, int n,
        const float* __restrict__ rsU, const float* __restrict__ riU,
        const float* __restrict__ rsL, const float* __restrict__ riL,
        const float* __restrict__ cus, const float* __restrict__ cui,
        const float* __restrict__ cls, const float* __restrict__ cli,
        const float* __restrict__ bvec,
        bf16_t* __restrict__ Ab, float* __restrict__ av) {
    int r = blockIdx.x;
    int j0 = threadIdx.x * 8;
    bf16_t* Ar = Ab + swz(r, j0, KTILES);
    if (r >= 2 * n) {
        bf16x8 z;
        #pragma unroll
        for (int u = 0; u < 8; ++u) z[u] = (bf16_t)0.f;
        *(bf16x8*)Ar = z;
        if (threadIdx.x == 0) av[r] = 0.f;
        return;
    }
    bool isU = r < n;
    int i = isU ? r : (r - n);
    const float* Wr = W + (size_t)i * 2048;
    float rs = 1.f, ri = 0.f;
    if (rsU) { rs = isU ? rsU[i] : rsL[i]; ri = isU ? riU[i] : riL[i]; }
    const float* ps = isU ? cus : cls;
    const float* ns = isU ? cls : cus;
    const float* pi = isU ? cui : cli;
    const float* ni = isU ? cli : cui;
    float a = 0.f;
    bf16x8 v;
    #pragma unroll
    for (int u = 0; u < 8; ++u) {
        float w = rs * Wr[j0 + u];
        float pos = fmaxf(w, 0.f), neg = fminf(w, 0.f);
        float mx = pos * ps[j0 + u] + neg * ns[j0 + u];
        v[u] = (bf16_t)mx;
        a += pos * pi[j0 + u] + neg * ni[j0 + u] + mx * bvec[j0 + u];
    }
    *(bf16x8*)Ar = v;
    float acc[1] = {a};
    block_reduce_sum<1>(acc);
    if (threadIdx.x == 0) av[r] = acc[0] + rs * b[i] + ri;
}

// diag-SPU step on GEMM output: Cb fp32 (split slabs) -> swizzled bf16 Ab,
// av += intercept dot + mixed . bvec (fused biascol)
__global__ __launch_bounds__(256) void k_colmix16(
        const float* __restrict__ Cb, int ldc, int splits, size_t sstride, int Rhalf,
        const float* __restrict__ cus, const float* __restrict__ cui,
        const float* __restrict__ cls, const float* __restrict__ cli,
        const float* __restrict__ bvec,
        bf16_t* __restrict__ Ab, float* __restrict__ av) {
    int r = blockIdx.x;
    bool isU = r < Rhalf;
    const float* Cr = Cb + (size_t)r * ldc;
    int j0 = threadIdx.x * 8;
    bf16_t* Ar = Ab + swz(r, j0, KTILES);
    const float* ps = isU ? cus : cls;
    const float* ns = isU ? cls : cus;
    const float* pi = isU ? cui : cli;
    const float* ni = isU ? cli : cui;
    float a = 0.f;
    bf16x8 v;
    #pragma unroll
    for (int u = 0; u < 8; ++u) {
        float w = 0.f;
        for (int s = 0; s < splits; ++s) w += Cr[s * sstride + j0 + u];
        float pos = fmaxf(w, 0.f), neg = fminf(w, 0.f);
        float mx = pos * ps[j0 + u] + neg * ns[j0 + u];
        v[u] = (bf16_t)mx;
        a += pos * pi[j0 + u] + neg * ni[j0 + u] + mx * bvec[j0 + u];
    }
    *(bf16x8*)Ar = v;
    float acc[1] = {a};
    block_reduce_sum<1>(acc);
    if (threadIdx.x == 0) av[r] += acc[0];
}

// final c0 step: Cb fp32 splits summed + av -> U=min(U,v) / L=max(L,v)
__global__ __launch_bounds__(256) void k_reduce16(
        const float* __restrict__ Cb, int ldc, int m, int n,
        int splits, size_t sstride,
        const float* __restrict__ av,
        const float* __restrict__ ubn, const float* __restrict__ lbn,
        float* __restrict__ U, float* __restrict__ L) {
    int r = blockIdx.x;
    bool isU = r < n;
    int i = isU ? r : (r - n);
    const float* Cr = Cb + (size_t)r * ldc;
    const float* p = isU ? ubn : lbn;
    const float* q = isU ? lbn : ubn;
    float acc[1] = {0.f};
    for (int j = threadIdx.x; j < m; j += 256) {
        float w = 0.f;
        for (int s = 0; s < splits; ++s) w += Cr[s * sstride + j];
        acc[0] += fmaxf(w, 0.f) * p[j] + fminf(w, 0.f) * q[j];
    }
    block_reduce_sum<1>(acc);
    if (threadIdx.x == 0) {
        float v = acc[0] + av[r];
        if (isU) U[i] = fminf(U[i], v);
        else     L[i] = fmaxf(L[i], v);
    }
}

__global__ void k_final_min(const float* __restrict__ l, int n, float* __restrict__ out) {
    float v = 3.4e38f;
    for (int j = threadIdx.x; j < n; j += 64) v = fminf(v, l[j]);
    #pragma unroll
    for (int o = 32; o > 0; o >>= 1) v = fminf(v, __shfl_down(v, o, 64));
    if (threadIdx.x == 0) out[0] = v;
}

// ---------------- bf16 MFMA GEMM, global_load_lds staging ----------------
// C[z] (fp32, ldc, slab sstride) = A(M x K swz) @ Bt(N x K swz)^T over k-tiles
// [z*nk, z*nk+nk). 128x128 tile, 4 waves, 4x4 mfma_f32_16x16x32_bf16 each.
__global__ __launch_bounds__(256) void k_gemm16(
        const bf16_t* __restrict__ A, const bf16_t* __restrict__ Bt,
        float* __restrict__ C, int ldc, size_t sstride, int nk) {
    __shared__ __align__(16) bf16_t As[4096];
    __shared__ __align__(16) bf16_t Bs[4096];
    int tid = threadIdx.x, lane = tid & 63, w = tid >> 6;
    int wm = w & 1, wn = w >> 1;
    int tr0 = blockIdx.y * 8, tc0 = blockIdx.x * 8;
    int kt0 = blockIdx.z * nk;

    const bf16_t* a0 = A + (((size_t)(tr0 + w)     * KTILES + kt0) << 9) + lane * 8;
    const bf16_t* a1 = A + (((size_t)(tr0 + w + 4) * KTILES + kt0) << 9) + lane * 8;
    const bf16_t* b0 = Bt + (((size_t)(tc0 + w)     * KTILES + kt0) << 9) + lane * 8;
    const bf16_t* b1 = Bt + (((size_t)(tc0 + w + 4) * KTILES + kt0) << 9) + lane * 8;
    bf16_t* lA0 = &As[w * 512];
    bf16_t* lA1 = &As[(w + 4) * 512];
    bf16_t* lB0 = &Bs[w * 512];
    bf16_t* lB1 = &Bs[(w + 4) * 512];

    f32x4 acc[4][4];
    #pragma unroll
    for (int i = 0; i < 4; ++i)
        #pragma unroll
        for (int j = 0; j < 4; ++j) acc[i][j] = (f32x4){0.f, 0.f, 0.f, 0.f};

    for (int kk = 0; kk < nk; ++kk) {
        g2l16(a0 + (size_t)kk * 512, lA0);
        g2l16(a1 + (size_t)kk * 512, lA1);
        g2l16(b0 + (size_t)kk * 512, lB0);
        g2l16(b1 + (size_t)kk * 512, lB1);
        __syncthreads();
        bf16x8 af[4], bfr[4];
        #pragma unroll
        for (int i = 0; i < 4; ++i)
            af[i] = *(const bf16x8*)(&As[(wm * 4 + i) * 512 + lane * 8]);
        #pragma unroll
        for (int j = 0; j < 4; ++j)
            bfr[j] = *(const bf16x8*)(&Bs[(wn * 4 + j) * 512 + lane * 8]);
        #pragma unroll
        for (int i = 0; i < 4; ++i)
            #pragma unroll
            for (int j = 0; j < 4; ++j)
                acc[i][j] = mfma16(af[i], bfr[j], acc[i][j]);
        __syncthreads();
    }
    // C/D layout: col = lane&15, row = (lane>>4)*4 + reg
    float* Cz = C + (size_t)blockIdx.z * sstride;
    int cq = lane >> 4, cn = lane & 15;
    size_t row0 = (size_t)blockIdx.y * 128;
    size_t col0 = (size_t)blockIdx.x * 128;
    #pragma unroll
    for (int i = 0; i < 4; ++i) {
        size_t gr0 = row0 + wm * 64 + i * 16 + cq * 4;
        #pragma unroll
        for (int j = 0; j < 4; ++j) {
            size_t gc = col0 + wn * 64 + j * 16 + cn;
            #pragma unroll
            for (int rg = 0; rg < 4; ++rg)
                Cz[(gr0 + rg) * (size_t)ldc + gc] = acc[i][j][rg];
        }
    }
}

// ---------------- host launch ----------------

extern "C" void kernel_launch(void* const* d_in, const int* in_sizes, int n_in,
                              void* d_out, int out_size, void* d_ws, size_t ws_size,
                              hipStream_t stream) {
    (void)in_sizes; (void)n_in; (void)out_size; (void)ws_size;
    const float* x   = (const float*)d_in[0];
    const float* eps = (const float*)d_in[1];
    const float* W1  = (const float*)d_in[2];
    const float* B1  = (const float*)d_in[3];
    const float* W2  = (const float*)d_in[4];
    const float* B2  = (const float*)d_in[5];
    const float* W3  = (const float*)d_in[6];
    const float* B3  = (const float*)d_in[7];
    const float* W4  = (const float*)d_in[8];
    const float* B4  = (const float*)d_in[9];
    float* out = (float*)d_out;

    const int H = 2048, DIN = 784, DOUT = 10;
    const int NP1 = 896;           // DIN padded to x128
    const int LDN = 800;           // fp32 layer-1 stride
    const int MP4 = 128;           // layer-4 row pad

    float* ws = (float*)d_ws;
    size_t off = 0;
    auto alloc = [&](size_t nf) -> float* {
        float* p = ws + off;
        off += (nf + 3) & ~(size_t)3;
        return p;
    };
    float* ubn = alloc(DIN);
    float* lbn = alloc(DIN);
    float* bU1 = alloc(H); float* bL1 = alloc(H);
    float* us1 = alloc(H); float* ui1 = alloc(H); float* ls1 = alloc(H); float* li1 = alloc(H);
    float* pU1 = alloc(H); float* pL1 = alloc(H);
    float* bU2 = alloc(H); float* bL2 = alloc(H);
    float* us2 = alloc(H); float* ui2 = alloc(H); float* ls2 = alloc(H); float* li2 = alloc(H);
    float* pU2 = alloc(H); float* pL2 = alloc(H);
    float* bU3 = alloc(H); float* bL3 = alloc(H);
    float* us3 = alloc(H); float* ui3 = alloc(H); float* ls3 = alloc(H); float* li3 = alloc(H);
    float* pU3 = alloc(H); float* pL3 = alloc(H);
    float* bU4 = alloc(32); float* bL4 = alloc(32);
    float* av  = alloc(2 * H);
    bf16_t* Ab  = (bf16_t*)alloc((size_t)2 * H * H / 2);       // 4096 x 2048 bf16 swz
    bf16_t* W1t = (bf16_t*)alloc((size_t)NP1 * H / 2);         // 896 x 2048 bf16 swz
    bf16_t* W2t = (bf16_t*)alloc((size_t)H * H / 2);
    bf16_t* W3t = (bf16_t*)alloc((size_t)H * H / 2);
    float* Cb = alloc((size_t)2 * H * H);                      // 8M floats (32 MB)
    float* A32 = Cb;                                           // layer-1 fp32 scratch

    dim3 blk(256);
    auto gemm = [&](const bf16_t* A, const bf16_t* Bt, float* C, int N, int Mpad, int splits) {
        dim3 g(N / 128, Mpad / 128, splits);
        k_gemm16<<<g, blk, 0, stream>>>(A, Bt, C, N, (size_t)Mpad * N, KTILES / splits);
    };

    // weight transpose/convert/swizzle
    k_wT<<<dim3(H / 64, NP1 / 64), blk, 0, stream>>>(W1, DIN, DIN, W1t);
    k_wT<<<dim3(H / 64, H / 64), blk, 0, stream>>>(W2, H, H, W2t);
    k_wT<<<dim3(H / 64, H / 64), blk, 0, stream>>>(W3, H, H, W3t);

    k_input_bounds<<<dim3((DIN + 255) / 256), blk, 0, stream>>>(x, eps, DIN, ubn, lbn);

    // ======== Layer 1 (fp32 exact) ========
    k_interval_affine<<<dim3(H), blk, 0, stream>>>(W1, B1, ubn, lbn, DIN, bU1, bL1);
    k_spu<<<dim3(H / 256), blk, 0, stream>>>(bU1, bL1, H, us1, ui1, ls1, li1, pU1, pL1);
    k_prep<<<dim3(2 * H), blk, 0, stream>>>(W1, B1, H, DIN, LDN, us1, ui1, ls1, li1, A32);
    k_reduce_c0<<<dim3(2 * H), blk, 0, stream>>>(A32, LDN, DIN, H, ubn, lbn, pU1, pL1);

    size_t ssM = (size_t)2 * H * NP1;   // medium-GEMM split slab
    size_t ss4H = (size_t)MP4 * H;      // layer-4 N=H slab
    size_t ss4N = (size_t)MP4 * NP1;    // layer-4 N=NP1 slab

    // ======== Layer 2 ========
    k_interval_affine<<<dim3(H), blk, 0, stream>>>(W2, B2, pU1, pL1, H, bU2, bL2);
    k_prep16<<<dim3(2 * H), blk, 0, stream>>>(W2, B2, H,
        nullptr, nullptr, nullptr, nullptr, us1, ui1, ls1, li1, B1, Ab, av);
    gemm(Ab, W1t, Cb, NP1, 2 * H, 2);
    k_reduce16<<<dim3(2 * H), blk, 0, stream>>>(Cb, NP1, DIN, H, 2, ssM, av, ubn, lbn, bU2, bL2);
    k_spu<<<dim3(H / 256), blk, 0, stream>>>(bU2, bL2, H, us2, ui2, ls2, li2, pU2, pL2);
    k_prep16<<<dim3(2 * H), blk, 0, stream>>>(W2, B2, H,
        us2, ui2, ls2, li2, us1, ui1, ls1, li1, B1, Ab, av);
    gemm(Ab, W1t, Cb, NP1, 2 * H, 2);
    k_reduce16<<<dim3(2 * H), blk, 0, stream>>>(Cb, NP1, DIN, H, 2, ssM, av, ubn, lbn, pU2, pL2);

    // ======== Layer 3 ========
    k_interval_affine<<<dim3(H), blk, 0, stream>>>(W3, B3, pU2, pL2, H, bU3, bL3);
    k_prep16<<<dim3(2 * H), blk, 0, stream>>>(W3, B3, H,
        nullptr, nullptr, nullptr, nullptr, us2, ui2, ls2, li2, B2, Ab, av);
    gemm(Ab, W2t, Cb, H, 2 * H, 1);
    k_colmix16<<<dim3(2 * H), blk, 0, stream>>>(Cb, H, 1, 0, H,
        us1, ui1, ls1, li1, B1, Ab, av);
    gemm(Ab, W1t, Cb, NP1, 2 * H, 2);
    k_reduce16<<<dim3(2 * H), blk, 0, stream>>>(Cb, NP1, DIN, H, 2, ssM, av, ubn, lbn, bU3, bL3);
    k_spu<<<dim3(H / 256), blk, 0, stream>>>(bU3, bL3, H, us3, ui3, ls3, li3, pU3, pL3);
    k_prep16<<<dim3(2 * H), blk, 0, stream>>>(W3, B3, H,
        us3, ui3, ls3, li3, us2, ui2, ls2, li2, B2, Ab, av);
    gemm(Ab, W2t, Cb, H, 2 * H, 1);
    k_colmix16<<<dim3(2 * H), blk, 0, stream>>>(Cb, H, 1, 0, H,
        us1, ui1, ls1, li1, B1, Ab, av);
    gemm(Ab, W1t, Cb, NP1, 2 * H, 2);
    k_reduce16<<<dim3(2 * H), blk, 0, stream>>>(Cb, NP1, DIN, H, 2, ssM, av, ubn, lbn, pU3, pL3);

    // ======== Layer 4 (M = 20 padded to 128, split-K 16) ========
    k_interval_affine<<<dim3(DOUT), blk, 0, stream>>>(W4, B4, pU3, pL3, H, bU4, bL4);
    k_prep16<<<dim3(MP4), blk, 0, stream>>>(W4, B4, DOUT,
        nullptr, nullptr, nullptr, nullptr, us3, ui3, ls3, li3, B3, Ab, av);
    gemm(Ab, W3t, Cb, H, MP4, 16);
    k_colmix16<<<dim3(MP4), blk, 0, stream>>>(Cb, H, 16, ss4H, DOUT,
        us2, ui2, ls2, li2, B2, Ab, av);
    gemm(Ab, W2t, Cb, H, MP4, 16);
    k_colmix16<<<dim3(MP4), blk, 0, stream>>>(Cb, H, 16, ss4H, DOUT,
        us1, ui1, ls1, li1, B1, Ab, av);
    gemm(Ab, W1t, Cb, NP1, MP4, 16);
    k_reduce16<<<dim3(2 * DOUT), blk, 0, stream>>>(Cb, NP1, DIN, DOUT, 16, ss4N,
        av, ubn, lbn, bU4, bL4);

    k_final_min<<<dim3(1), dim3(64), 0, stream>>>(bL4, DOUT, out);
}

// Round 4
// 656.833 us; speedup vs baseline: 4.5982x; 1.2280x over previous
//
#include <hip/hip_runtime.h>
#include <cstdint>
#include <cstddef>

#define MEAN_C 0.1307f
#define SIGMA_C 0.3081f
#define SIG_SCALE_C 5.0f

typedef __bf16 bf16_t;
typedef __bf16 bf16x8 __attribute__((ext_vector_type(8)));
typedef float f32x4 __attribute__((ext_vector_type(4)));

__device__ __forceinline__ f32x4 mfma16(bf16x8 a, bf16x8 b, f32x4 c) {
    return __builtin_amdgcn_mfma_f32_16x16x32_bf16(a, b, c, 0, 0, 0);
}

typedef const __attribute__((address_space(1))) void* gvp;
typedef __attribute__((address_space(3))) void* lvp;
__device__ __forceinline__ void g2l16(const void* g, void* l) {
    __builtin_amdgcn_global_load_lds((gvp)g, (lvp)l, 16, 0, 0);
}

// swizzled bf16 operand layout: 16x32 tiles (1KB); chunk index within tile =
// lane = (k-chunk)*16 + row  (16B each). offset(r,k), K = ktiles*32.
__device__ __forceinline__ size_t swz(int r, int k, int ktiles) {
    return (((size_t)(r >> 4) * ktiles + (k >> 5)) << 9)
         + (((k >> 3) & 3) << 7) + ((r & 15) << 3) + (k & 7);
}

#define KTILES 64   // K = 2048

// ---------------- device helpers ----------------

__device__ __forceinline__ float sigmoidf_(float x) {
    if (x >= 0.f) { float e = __expf(-x); return 1.f / (1.f + e); }
    float e = __expf(x); return e / (1.f + e);
}

__device__ __forceinline__ float spu_f(float x) {
    return (x >= 0.f) ? (x * x - 0.5f) : (sigmoidf_(-x) - 1.f);
}

__device__ __forceinline__ float wave_sum(float a) {
    #pragma unroll
    for (int o = 32; o > 0; o >>= 1) a += __shfl_xor(a, o, 64);
    return a;
}

// ---------------- small kernels ----------------

__global__ void k_input_bounds(const float* __restrict__ x, const float* __restrict__ eps,
                               int n, float* __restrict__ ubn, float* __restrict__ lbn) {
    int i = blockIdx.x * blockDim.x + threadIdx.x;
    if (i >= n) return;
    float e = eps[0];
    float ub = fminf(x[i] + e, 1.f);
    float lb = fmaxf(x[i] - e, 0.f);
    ubn[i] = (ub - MEAN_C) / SIGMA_C;
    lbn[i] = (lb - MEAN_C) / SIGMA_C;
}

// wave-per-row interval bound: u_i = sum_j (W>0?U:L)*W + b ; l_i symmetric
__global__ __launch_bounds__(256) void k_interval_affine(
        const float* __restrict__ W, const float* __restrict__ b,
        const float* __restrict__ U, const float* __restrict__ L,
        int m, int nrows, float* __restrict__ uo, float* __restrict__ lo) {
    int r = (blockIdx.x << 2) + (threadIdx.x >> 6);
    if (r >= nrows) return;
    int lane = threadIdx.x & 63;
    const f32x4* Wr = (const f32x4*)(W + (size_t)r * m);
    const f32x4* U4 = (const f32x4*)U;
    const f32x4* L4 = (const f32x4*)L;
    int nf4 = m >> 2;
    float au = 0.f, al = 0.f;
    for (int j = lane; j < nf4; j += 64) {
        f32x4 wv = Wr[j], uu = U4[j], ll = L4[j];
        #pragma unroll
        for (int u = 0; u < 4; ++u) {
            float w = wv[u];
            float hi = (w > 0.f) ? uu[u] : ll[u];
            float lo2 = (w > 0.f) ? ll[u] : uu[u];
            au = fmaf(w, hi, au);
            al = fmaf(w, lo2, al);
        }
    }
    au = wave_sum(au); al = wave_sum(al);
    if (lane == 0) { uo[r] = au + b[r]; lo[r] = al + b[r]; }
}

__global__ void k_spu(const float* __restrict__ Uin, const float* __restrict__ Lin, int n,
                      float* __restrict__ us, float* __restrict__ ui,
                      float* __restrict__ ls, float* __restrict__ li,
                      float* __restrict__ nu, float* __restrict__ nl) {
    int i = blockIdx.x * blockDim.x + threadIdx.x;
    if (i >= n) return;
    float ux = Uin[i], lx = Lin[i];
    float uy = spu_f(ux), ly = spu_f(lx);
    float new_ub = fmaxf(uy, ly);
    float sj = (uy - ly) / (ux - lx);
    float ij = uy - sj * ux;
    bool right = lx > 0.f;
    bool left = ux <= 0.f;
    bool crossing = (!left) && (!right);
    float mid = 0.5f * (ux + lx);
    float sp = 2.f * mid, ip = -mid * mid - 0.5f;
    float sm = sigmoidf_(mid);
    float ssm = -sm * (1.f - sm);
    float ism = -sm - ssm * mid;
    float new_lb = crossing ? -0.5f : fminf(uy, ly);
    float spu_s = 2.f * ux, ipu = -ux * ux - 0.5f;
    float limit = spu_s * lx + ipu;
    float clm = (fabsf(lx) > ux) ? 1.f : 0.f;
    float clp = sigmoidf_((clm - 0.5f) * 2.f * SIG_SCALE_C) * (ly - limit) + limit;
    bool ptm = clp < -0.5f;
    float D = 4.f * lx * lx - 4.f * clp - 2.f;
    float x2 = (2.f * lx + sqrtf(fmaxf(D, 0.f))) * 0.5f;
    float spt = 2.f * x2, ipt = -x2 * x2 - 0.5f;
    float sjn = (clp + 0.5f) / lx;
    float ijn = -0.5f;
    float s_cl = ptm ? spt : sjn;
    float i_cl = ptm ? ipt : ijn;
    float sl = sigmoidf_(lx);
    float ssl = -sl * (1.f - sl);
    float isl = -sl - ssl * lx;
    float stv = ssl * ux + isl - uy;
    float Lb = lx, Rb = 0.f;
    #pragma unroll
    for (int t = 0; t < 10; ++t) {
        float mm = 0.5f * (Lb + Rb);
        float smm = sigmoidf_(mm);
        float sms = -smm * (1.f - smm);
        float smi = -smm - sms * mm;
        bool mask = (sms * ux + smi - uy) > 0.f;
        Lb = mask ? mm : Lb;
        Rb = mask ? Rb : mm;
    }
    float scp = sigmoidf_(-SIG_SCALE_C) * (Lb - lx) + lx;
    float sc = sigmoidf_(scp);
    float ssc = -sc * (1.f - sc);
    float isc = -sc - ssc * scp;
    bool up = stv > 0.f;
    float s_cu = up ? ssc : sj;
    float i_cu = up ? isc : ij;
    float usv, uiv, lsv, liv;
    if (right)      { usv = sj;   uiv = ij;   lsv = sp;   liv = ip;   }
    else if (left)  { usv = ssm;  uiv = ism;  lsv = sj;   liv = ij;   }
    else            { usv = s_cu; uiv = i_cu; lsv = s_cl; liv = i_cl; }
    us[i] = usv; ui[i] = uiv; ls[i] = lsv; li[i] = liv;
    nu[i] = new_ub; nl[i] = new_lb;
}

// layer-1 fused backsub: wave per row r of 2n; v = sum sign-split(rs*W) . (ubn/lbn)
// + rs*b + ri; U=min(U,v) / L=max(L,v). No intermediate matrix.
__global__ __launch_bounds__(256) void k_bsub1(
        const float* __restrict__ W, const float* __restrict__ b, int n, int m,
        const float* __restrict__ rsU, const float* __restrict__ riU,
        const float* __restrict__ rsL, const float* __restrict__ riL,
        const float* __restrict__ ubn, const float* __restrict__ lbn,
        float* __restrict__ U, float* __restrict__ L) {
    int r = (blockIdx.x << 2) + (threadIdx.x >> 6);
    if (r >= 2 * n) return;
    int lane = threadIdx.x & 63;
    bool isU = r < n;
    int i = isU ? r : r - n;
    float rs = isU ? rsU[i] : rsL[i];
    float ri = isU ? riU[i] : riL[i];
    const f32x4* Wr = (const f32x4*)(W + (size_t)i * m);
    const f32x4* P = (const f32x4*)(isU ? ubn : lbn);
    const f32x4* Q = (const f32x4*)(isU ? lbn : ubn);
    int nf4 = m >> 2;
    float a = 0.f;
    for (int j = lane; j < nf4; j += 64) {
        f32x4 wv = Wr[j], pp = P[j], qq = Q[j];
        #pragma unroll
        for (int u = 0; u < 4; ++u) {
            float w = rs * wv[u];
            a += fmaxf(w, 0.f) * pp[u] + fminf(w, 0.f) * qq[u];
        }
    }
    a = wave_sum(a);
    if (lane == 0) {
        float v = a + rs * b[i] + ri;
        if (isU) U[i] = fminf(U[i], v);
        else     L[i] = fmaxf(L[i], v);
    }
}

// ---------------- bf16 producers (tile-shaped, swizzle-friendly) ----------------

// transpose + convert + swizzle: W (K x N real, ldw) fp32 -> Wt swizzled (Npad x K)
__global__ __launch_bounds__(256) void k_wT(
        const float* __restrict__ W, int N, int ldw,
        bf16_t* __restrict__ Wt) {
    __shared__ bf16_t t[64][72];
    int k0 = blockIdx.x * 64, n0 = blockIdx.y * 64;
    int tid = threadIdx.x;
    int r = tid >> 2;
    int c0 = (tid & 3) * 16;
    const float* Wr = W + (size_t)(k0 + r) * ldw;
    #pragma unroll
    for (int c = 0; c < 16; ++c) {
        int gn = n0 + c0 + c;
        float vv = (gn < N) ? Wr[gn] : 0.f;
        t[c0 + c][r] = (bf16_t)vv;
    }
    __syncthreads();
    #pragma unroll
    for (int p = 0; p < 2; ++p) {
        int c = tid + p * 256;
        int lr = c & 63, lq = c >> 6;
        bf16x8 v;
        #pragma unroll
        for (int u = 0; u < 8; ++u) v[u] = t[lr][lq * 8 + u];
        *(bf16x8*)(Wt + swz(n0 + lr, k0 + lq * 8, KTILES)) = v;
    }
}

// prep: one 16-row tile per block; lane owns chunk lane of each k-tile
// (row=lane&15, kchunk=lane>>4) -> wave stores are contiguous 1KB.
// av[r] = intercept-mix dot + mixed.bvec dot + rs*b + ri. rows >= 2n zeroed.
__global__ __launch_bounds__(256) void k_prep16(
        const float* __restrict__ W, const float* __restrict__ b, int n,
        const float* __restrict__ rsU, const float* __restrict__ riU,
        const float* __restrict__ rsL, const float* __restrict__ riL,
        const float* __restrict__ cus, const float* __restrict__ cui,
        const float* __restrict__ cls, const float* __restrict__ cli,
        const float* __restrict__ bvec,
        bf16_t* __restrict__ Ab, float* __restrict__ av) {
    int rt = blockIdx.x;
    int tid = threadIdx.x, lane = tid & 63, wid = tid >> 6;
    int mrow = lane & 15, q = lane >> 4;
    int r = rt * 16 + mrow;
    bool act = r < 2 * n;
    bool isU = r < n;
    int i = act ? (isU ? r : r - n) : 0;
    float rs = 1.f;
    if (rsU) rs = isU ? rsU[i] : rsL[i];
    if (!act) rs = 0.f;
    const float* Wr = W + (size_t)i * 2048;
    const float* ps = isU ? cus : cls;
    const float* ns = isU ? cls : cus;
    const float* yi = isU ? cui : cli;
    const float* zi = isU ? cli : cui;
    float a = 0.f;
    bf16_t* Abase = Ab + ((size_t)rt * KTILES) * 512 + lane * 8;
    for (int kt = wid; kt < KTILES; kt += 4) {
        int k0 = kt * 32 + q * 8;
        f32x4 w0 = *(const f32x4*)(Wr + k0);
        f32x4 w1 = *(const f32x4*)(Wr + k0 + 4);
        f32x4 p0 = *(const f32x4*)(ps + k0), p1 = *(const f32x4*)(ps + k0 + 4);
        f32x4 q0 = *(const f32x4*)(ns + k0), q1 = *(const f32x4*)(ns + k0 + 4);
        f32x4 y0 = *(const f32x4*)(yi + k0), y1 = *(const f32x4*)(yi + k0 + 4);
        f32x4 z0 = *(const f32x4*)(zi + k0), z1 = *(const f32x4*)(zi + k0 + 4);
        f32x4 c0 = *(const f32x4*)(bvec + k0), c1 = *(const f32x4*)(bvec + k0 + 4);
        bf16x8 ov;
        #pragma unroll
        for (int u = 0; u < 4; ++u) {
            float w = rs * w0[u];
            float pos = fmaxf(w, 0.f), neg = fminf(w, 0.f);
            float mx = pos * p0[u] + neg * q0[u];
            ov[u] = (bf16_t)mx;
            a += pos * y0[u] + neg * z0[u] + mx * c0[u];
        }
        #pragma unroll
        for (int u = 0; u < 4; ++u) {
            float w = rs * w1[u];
            float pos = fmaxf(w, 0.f), neg = fminf(w, 0.f);
            float mx = pos * p1[u] + neg * q1[u];
            ov[4 + u] = (bf16_t)mx;
            a += pos * y1[u] + neg * z1[u] + mx * c1[u];
        }
        *(bf16x8*)(Abase + (size_t)kt * 512) = ov;
    }
    a += __shfl_xor(a, 16, 64);
    a += __shfl_xor(a, 32, 64);
    __shared__ float sh[4][16];
    if (lane < 16) sh[wid][lane] = a;
    __syncthreads();
    if (tid < 16) {
        int r2 = rt * 16 + tid;
        float tot = sh[0][tid] + sh[1][tid] + sh[2][tid] + sh[3][tid];
        if (r2 < 2 * n) {
            bool isU2 = r2 < n;
            int i2 = isU2 ? r2 : r2 - n;
            float rs2 = 1.f, ri2 = 0.f;
            if (rsU) { rs2 = isU2 ? rsU[i2] : rsL[i2]; ri2 = isU2 ? riU[i2] : riL[i2]; }
            av[r2] = tot + rs2 * b[i2] + ri2;
        } else {
            av[r2] = 0.f;
        }
    }
}

// colmix: same tile shape; input fp32 Cb (splits slabs summed), output swizzled
// bf16 Ab; av += dots via atomicAdd (grid.y = k-split).
__global__ __launch_bounds__(256) void k_colmix16(
        const float* __restrict__ Cb, int ldc, int splits, size_t sstride, int n,
        int tpb,
        const float* __restrict__ cus, const float* __restrict__ cui,
        const float* __restrict__ cls, const float* __restrict__ cli,
        const float* __restrict__ bvec,
        bf16_t* __restrict__ Ab, float* __restrict__ av) {
    int rt = blockIdx.x;
    int kt0 = blockIdx.y * tpb;
    int tid = threadIdx.x, lane = tid & 63, wid = tid >> 6;
    int mrow = lane & 15, q = lane >> 4;
    int r = rt * 16 + mrow;
    bool isU = r < n;
    const float* Cr = Cb + (size_t)r * ldc;
    const float* ps = isU ? cus : cls;
    const float* ns = isU ? cls : cus;
    const float* yi = isU ? cui : cli;
    const float* zi = isU ? cli : cui;
    float a = 0.f;
    bf16_t* Abase = Ab + ((size_t)rt * KTILES) * 512 + lane * 8;
    for (int kt = kt0 + wid; kt < kt0 + tpb; kt += 4) {
        int k0 = kt * 32 + q * 8;
        f32x4 s0 = {0.f, 0.f, 0.f, 0.f}, s1 = {0.f, 0.f, 0.f, 0.f};
        for (int s = 0; s < splits; ++s) {
            s0 += *(const f32x4*)(Cr + s * sstride + k0);
            s1 += *(const f32x4*)(Cr + s * sstride + k0 + 4);
        }
        f32x4 p0 = *(const f32x4*)(ps + k0), p1 = *(const f32x4*)(ps + k0 + 4);
        f32x4 q0 = *(const f32x4*)(ns + k0), q1 = *(const f32x4*)(ns + k0 + 4);
        f32x4 y0 = *(const f32x4*)(yi + k0), y1 = *(const f32x4*)(yi + k0 + 4);
        f32x4 z0 = *(const f32x4*)(zi + k0), z1 = *(const f32x4*)(zi + k0 + 4);
        f32x4 c0 = *(const f32x4*)(bvec + k0), c1 = *(const f32x4*)(bvec + k0 + 4);
        bf16x8 ov;
        #pragma unroll
        for (int u = 0; u < 4; ++u) {
            float w = s0[u];
            float pos = fmaxf(w, 0.f), neg = fminf(w, 0.f);
            float mx = pos * p0[u] + neg * q0[u];
            ov[u] = (bf16_t)mx;
            a += pos * y0[u] + neg * z0[u] + mx * c0[u];
        }
        #pragma unroll
        for (int u = 0; u < 4; ++u) {
            float w = s1[u];
            float pos = fmaxf(w, 0.f), neg = fminf(w, 0.f);
            float mx = pos * p1[u] + neg * q1[u];
            ov[4 + u] = (bf16_t)mx;
            a += pos * y1[u] + neg * z1[u] + mx * c1[u];
        }
        *(bf16x8*)(Abase + (size_t)kt * 512) = ov;
    }
    a += __shfl_xor(a, 16, 64);
    a += __shfl_xor(a, 32, 64);
    __shared__ float sh[4][16];
    if (lane < 16) sh[wid][lane] = a;
    __syncthreads();
    if (tid < 16) {
        float tot = sh[0][tid] + sh[1][tid] + sh[2][tid] + sh[3][tid];
        atomicAdd(&av[rt * 16 + tid], tot);
    }
}

// final c0 step: wave per row; v = sign-split(sum slabs) . (ubn/lbn) + av[r]
__global__ __launch_bounds__(256) void k_reduce16(
        const float* __restrict__ Cb, int ldc, int m, int n,
        int splits, size_t sstride,
        const float* __restrict__ av,
        const float* __restrict__ ubn, const float* __restrict__ lbn,
        float* __restrict__ U, float* __restrict__ L) {
    int r = (blockIdx.x << 2) + (threadIdx.x >> 6);
    if (r >= 2 * n) return;
    int lane = threadIdx.x & 63;
    bool isU = r < n;
    int i = isU ? r : r - n;
    const float* Cr = Cb + (size_t)r * ldc;
    const f32x4* P = (const f32x4*)(isU ? ubn : lbn);
    const f32x4* Q = (const f32x4*)(isU ? lbn : ubn);
    int nf4 = m >> 2;
    float a = 0.f;
    for (int j = lane; j < nf4; j += 64) {
        f32x4 wv = {0.f, 0.f, 0.f, 0.f};
        for (int s = 0; s < splits; ++s) wv += *(const f32x4*)(Cr + s * sstride + j * 4);
        f32x4 pp = P[j], qq = Q[j];
        #pragma unroll
        for (int u = 0; u < 4; ++u)
            a += fmaxf(wv[u], 0.f) * pp[u] + fminf(wv[u], 0.f) * qq[u];
    }
    a = wave_sum(a);
    if (lane == 0) {
        float v = a + av[r];
        if (isU) U[i] = fminf(U[i], v);
        else     L[i] = fmaxf(L[i], v);
    }
}

__global__ void k_final_min(const float* __restrict__ l, int n, float* __restrict__ out) {
    float v = 3.4e38f;
    for (int j = threadIdx.x; j < n; j += 64) v = fminf(v, l[j]);
    #pragma unroll
    for (int o = 32; o > 0; o >>= 1) v = fminf(v, __shfl_down(v, o, 64));
    if (threadIdx.x == 0) out[0] = v;
}

// ---------------- bf16 MFMA GEMM, global_load_lds staging ----------------
__global__ __launch_bounds__(256) void k_gemm16(
        const bf16_t* __restrict__ A, const bf16_t* __restrict__ Bt,
        float* __restrict__ C, int ldc, size_t sstride, int nk) {
    __shared__ __align__(16) bf16_t As[4096];
    __shared__ __align__(16) bf16_t Bs[4096];
    int tid = threadIdx.x, lane = tid & 63, w = tid >> 6;
    int wm = w & 1, wn = w >> 1;
    int tr0 = blockIdx.y * 8, tc0 = blockIdx.x * 8;
    int kt0 = blockIdx.z * nk;

    const bf16_t* a0 = A + (((size_t)(tr0 + w)     * KTILES + kt0) << 9) + lane * 8;
    const bf16_t* a1 = A + (((size_t)(tr0 + w + 4) * KTILES + kt0) << 9) + lane * 8;
    const bf16_t* b0 = Bt + (((size_t)(tc0 + w)     * KTILES + kt0) << 9) + lane * 8;
    const bf16_t* b1 = Bt + (((size_t)(tc0 + w + 4) * KTILES + kt0) << 9) + lane * 8;
    bf16_t* lA0 = &As[w * 512];
    bf16_t* lA1 = &As[(w + 4) * 512];
    bf16_t* lB0 = &Bs[w * 512];
    bf16_t* lB1 = &Bs[(w + 4) * 512];

    f32x4 acc[4][4];
    #pragma unroll
    for (int i = 0; i < 4; ++i)
        #pragma unroll
        for (int j = 0; j < 4; ++j) acc[i][j] = (f32x4){0.f, 0.f, 0.f, 0.f};

    for (int kk = 0; kk < nk; ++kk) {
        g2l16(a0 + (size_t)kk * 512, lA0);
        g2l16(a1 + (size_t)kk * 512, lA1);
        g2l16(b0 + (size_t)kk * 512, lB0);
        g2l16(b1 + (size_t)kk * 512, lB1);
        __syncthreads();
        bf16x8 af[4], bfr[4];
        #pragma unroll
        for (int i = 0; i < 4; ++i)
            af[i] = *(const bf16x8*)(&As[(wm * 4 + i) * 512 + lane * 8]);
        #pragma unroll
        for (int j = 0; j < 4; ++j)
            bfr[j] = *(const bf16x8*)(&Bs[(wn * 4 + j) * 512 + lane * 8]);
        #pragma unroll
        for (int i = 0; i < 4; ++i)
            #pragma unroll
            for (int j = 0; j < 4; ++j)
                acc[i][j] = mfma16(af[i], bfr[j], acc[i][j]);
        __syncthreads();
    }
    float* Cz = C + (size_t)blockIdx.z * sstride;
    int cq = lane >> 4, cn = lane & 15;
    size_t row0 = (size_t)blockIdx.y * 128;
    size_t col0 = (size_t)blockIdx.x * 128;
    #pragma unroll
    for (int i = 0; i < 4; ++i) {
        size_t gr0 = row0 + wm * 64 + i * 16 + cq * 4;
        #pragma unroll
        for (int j = 0; j < 4; ++j) {
            size_t gc = col0 + wn * 64 + j * 16 + cn;
            #pragma unroll
            for (int rg = 0; rg < 4; ++rg)
                Cz[(gr0 + rg) * (size_t)ldc + gc] = acc[i][j][rg];
        }
    }
}

// ---------------- host launch ----------------

extern "C" void kernel_launch(void* const* d_in, const int* in_sizes, int n_in,
                              void* d_out, int out_size, void* d_ws, size_t ws_size,
                              hipStream_t stream) {
    (void)in_sizes; (void)n_in; (void)out_size; (void)ws_size;
    const float* x   = (const float*)d_in[0];
    const float* eps = (const float*)d_in[1];
    const float* W1  = (const float*)d_in[2];
    const float* B1  = (const float*)d_in[3];
    const float* W2  = (const float*)d_in[4];
    const float* B2  = (const float*)d_in[5];
    const float* W3  = (const float*)d_in[6];
    const float* B3  = (const float*)d_in[7];
    const float* W4  = (const float*)d_in[8];
    const float* B4  = (const float*)d_in[9];
    float* out = (float*)d_out;

    const int H = 2048, DIN = 784, DOUT = 10;
    const int NP1 = 896;           // DIN padded to x128
    const int MP4 = 128;           // layer-4 row pad

    float* ws = (float*)d_ws;
    size_t off = 0;
    auto alloc = [&](size_t nf) -> float* {
        float* p = ws + off;
        off += (nf + 3) & ~(size_t)3;
        return p;
    };
    float* ubn = alloc(DIN);
    float* lbn = alloc(DIN);
    float* bU1 = alloc(H); float* bL1 = alloc(H);
    float* us1 = alloc(H); float* ui1 = alloc(H); float* ls1 = alloc(H); float* li1 = alloc(H);
    float* pU1 = alloc(H); float* pL1 = alloc(H);
    float* bU2 = alloc(H); float* bL2 = alloc(H);
    float* us2 = alloc(H); float* ui2 = alloc(H); float* ls2 = alloc(H); float* li2 = alloc(H);
    float* pU2 = alloc(H); float* pL2 = alloc(H);
    float* bU3 = alloc(H); float* bL3 = alloc(H);
    float* us3 = alloc(H); float* ui3 = alloc(H); float* ls3 = alloc(H); float* li3 = alloc(H);
    float* pU3 = alloc(H); float* pL3 = alloc(H);
    float* bU4 = alloc(32); float* bL4 = alloc(32);
    float* av  = alloc(2 * H);
    bf16_t* Ab  = (bf16_t*)alloc((size_t)2 * H * H / 2);       // 4096 x 2048 bf16 swz
    bf16_t* W1t = (bf16_t*)alloc((size_t)NP1 * H / 2);
    bf16_t* W2t = (bf16_t*)alloc((size_t)H * H / 2);
    bf16_t* W3t = (bf16_t*)alloc((size_t)H * H / 2);
    float* Cb = alloc((size_t)2 * H * H);                      // 8M floats (32 MB)

    dim3 blk(256);
    auto gemm = [&](const bf16_t* A, const bf16_t* Bt, float* C, int N, int Mpad, int splits) {
        dim3 g(N / 128, Mpad / 128, splits);
        k_gemm16<<<g, blk, 0, stream>>>(A, Bt, C, N, (size_t)Mpad * N, KTILES / splits);
    };

    // weight transpose/convert/swizzle
    k_wT<<<dim3(H / 64, NP1 / 64), blk, 0, stream>>>(W1, DIN, DIN, W1t);
    k_wT<<<dim3(H / 64, H / 64), blk, 0, stream>>>(W2, H, H, W2t);
    k_wT<<<dim3(H / 64, H / 64), blk, 0, stream>>>(W3, H, H, W3t);

    k_input_bounds<<<dim3((DIN + 255) / 256), blk, 0, stream>>>(x, eps, DIN, ubn, lbn);

    // ======== Layer 1 (fp32 exact) ========
    k_interval_affine<<<dim3(H / 4), blk, 0, stream>>>(W1, B1, ubn, lbn, DIN, H, bU1, bL1);
    k_spu<<<dim3(H / 256), blk, 0, stream>>>(bU1, bL1, H, us1, ui1, ls1, li1, pU1, pL1);
    k_bsub1<<<dim3(2 * H / 4), blk, 0, stream>>>(W1, B1, H, DIN,
        us1, ui1, ls1, li1, ubn, lbn, pU1, pL1);

    size_t ssM = (size_t)2 * H * NP1;   // medium-GEMM split slab
    size_t ss4H = (size_t)MP4 * H;      // layer-4 N=H slab
    size_t ss4N = (size_t)MP4 * NP1;    // layer-4 N=NP1 slab

    // ======== Layer 2 ========
    k_interval_affine<<<dim3(H / 4), blk, 0, stream>>>(W2, B2, pU1, pL1, H, H, bU2, bL2);
    k_prep16<<<dim3(2 * H / 16), blk, 0, stream>>>(W2, B2, H,
        nullptr, nullptr, nullptr, nullptr, us1, ui1, ls1, li1, B1, Ab, av);
    gemm(Ab, W1t, Cb, NP1, 2 * H, 2);
    k_reduce16<<<dim3(2 * H / 4), blk, 0, stream>>>(Cb, NP1, DIN, H, 2, ssM, av, ubn, lbn, bU2, bL2);
    k_spu<<<dim3(H / 256), blk, 0, stream>>>(bU2, bL2, H, us2, ui2, ls2, li2, pU2, pL2);
    k_prep16<<<dim3(2 * H / 16), blk, 0, stream>>>(W2, B2, H,
        us2, ui2, ls2, li2, us1, ui1, ls1, li1, B1, Ab, av);
    gemm(Ab, W1t, Cb, NP1, 2 * H, 2);
    k_reduce16<<<dim3(2 * H / 4), blk, 0, stream>>>(Cb, NP1, DIN, H, 2, ssM, av, ubn, lbn, pU2, pL2);

    // ======== Layer 3 ========
    k_interval_affine<<<dim3(H / 4), blk, 0, stream>>>(W3, B3, pU2, pL2, H, H, bU3, bL3);
    k_prep16<<<dim3(2 * H / 16), blk, 0, stream>>>(W3, B3, H,
        nullptr, nullptr, nullptr, nullptr, us2, ui2, ls2, li2, B2, Ab, av);
    gemm(Ab, W2t, Cb, H, 2 * H, 1);
    k_colmix16<<<dim3(2 * H / 16, 1), blk, 0, stream>>>(Cb, H, 1, 0, H, KTILES,
        us1, ui1, ls1, li1, B1, Ab, av);
    gemm(Ab, W1t, Cb, NP1, 2 * H, 2);
    k_reduce16<<<dim3(2 * H / 4), blk, 0, stream>>>(Cb, NP1, DIN, H, 2, ssM, av, ubn, lbn, bU3, bL3);
    k_spu<<<dim3(H / 256), blk, 0, stream>>>(bU3, bL3, H, us3, ui3, ls3, li3, pU3, pL3);
    k_prep16<<<dim3(2 * H / 16), blk, 0, stream>>>(W3, B3, H,
        us3, ui3, ls3, li3, us2, ui2, ls2, li2, B2, Ab, av);
    gemm(Ab, W2t, Cb, H, 2 * H, 1);
    k_colmix16<<<dim3(2 * H / 16, 1), blk, 0, stream>>>(Cb, H, 1, 0, H, KTILES,
        us1, ui1, ls1, li1, B1, Ab, av);
    gemm(Ab, W1t, Cb, NP1, 2 * H, 2);
    k_reduce16<<<dim3(2 * H / 4), blk, 0, stream>>>(Cb, NP1, DIN, H, 2, ssM, av, ubn, lbn, pU3, pL3);

    // ======== Layer 4 (M = 20 padded to 128, split-K 16, colmix k-split 8) ========
    k_interval_affine<<<dim3(3), blk, 0, stream>>>(W4, B4, pU3, pL3, H, DOUT, bU4, bL4);
    k_prep16<<<dim3(MP4 / 16), blk, 0, stream>>>(W4, B4, DOUT,
        nullptr, nullptr, nullptr, nullptr, us3, ui3, ls3, li3, B3, Ab, av);
    gemm(Ab, W3t, Cb, H, MP4, 16);
    k_colmix16<<<dim3(MP4 / 16, 8), blk, 0, stream>>>(Cb, H, 16, ss4H, DOUT, KTILES / 8,
        us2, ui2, ls2, li2, B2, Ab, av);
    gemm(Ab, W2t, Cb, H, MP4, 16);
    k_colmix16<<<dim3(MP4 / 16, 8), blk, 0, stream>>>(Cb, H, 16, ss4H, DOUT, KTILES / 8,
        us1, ui1, ls1, li1, B1, Ab, av);
    gemm(Ab, W1t, Cb, NP1, MP4, 16);
    k_reduce16<<<dim3((2 * DOUT + 3) / 4), blk, 0, stream>>>(Cb, NP1, DIN, DOUT, 16, ss4N,
        av, ubn, lbn, bU4, bL4);

    k_final_min<<<dim3(1), dim3(64), 0, stream>>>(bL4, DOUT, out);
}